// Round 1
// 1031.909 us; speedup vs baseline: 1.3488x; 1.3488x over previous
//
#include <hip/hip_runtime.h>

#define NB 4
#define SQL 1024
#define HDIM 1024
#define NHEAD 16
#define HEADD 64
#define NEXP 8
#define IDIM 2048
#define NTOK (NB*SQL)
#define CAPACITY 2048
#define ATT_SCALE 0.125f

typedef unsigned short u16;
typedef __attribute__((ext_vector_type(8))) short bf16x8;
typedef __attribute__((ext_vector_type(4))) float f32x4;

__device__ __forceinline__ u16 f2bf(float f) {
  union { float f; unsigned u; } x; x.f = f;
  unsigned r = (x.u + 0x7fffu + ((x.u >> 16) & 1u)) >> 16;
  return (u16)r;
}
__device__ __forceinline__ float bf2f(u16 b) {
  union { unsigned u; float f; } x; x.u = ((unsigned)b) << 16;
  return x.f;
}
__device__ __forceinline__ float wave_sum(float v) {
#pragma unroll
  for (int off = 32; off > 0; off >>= 1) v += __shfl_xor(v, off);
  return v;
}

// ---------------- fp32 -> bf16 row convert (x) ----------------
__global__ __launch_bounds__(256)
void cvt_bf16_kernel(const float* __restrict__ in, u16* __restrict__ out)
{
  size_t i = (size_t)blockIdx.x * 1024 + threadIdx.x * 4;
  float4 v = *(const float4*)&in[i];
  ushort4 o = {f2bf(v.x), f2bf(v.y), f2bf(v.z), f2bf(v.w)};
  *(ushort4*)&out[i] = o;
}

// ---------------- transpose+convert: in fp32 [e][R][C] -> out bf16 [e][C][R] ----------------
__global__ __launch_bounds__(256)
void transpose_cvt_kernel(const float* __restrict__ in, u16* __restrict__ out,
                          int R, int C)
{
  int e = blockIdx.z;
  const float* ine = in + (size_t)e * R * C;
  u16* oute = out + (size_t)e * R * C;
  __shared__ u16 Ts[32 * 34];
  int tx = threadIdx.x & 31, ty = threadIdx.x >> 5;
  int r0 = blockIdx.y * 32, c0 = blockIdx.x * 32;
#pragma unroll
  for (int qq = 0; qq < 4; ++qq) {
    int rr = ty + qq * 8;
    Ts[tx * 34 + rr] = f2bf(ine[(size_t)(r0 + rr) * C + c0 + tx]);
  }
  __syncthreads();
#pragma unroll
  for (int qq = 0; qq < 4; ++qq) {
    int cc = ty + qq * 8;
    oute[(size_t)(c0 + cc) * R + r0 + tx] = Ts[cc * 34 + tx];
  }
}

// ---------------- QKV projection: bf16 MFMA 128x128 tile, K=HDIM ----------------
// A = xbf [NTOK][HDIM] bf16; B = W^T [HDIM(out)][HDIM(in)] bf16; out fp32 scattered
// into q/k/v [B*NH][S][HD] with bias.
__global__ __launch_bounds__(256)
void qkv_mfma_kernel(const u16* __restrict__ xbf,
                     const u16* __restrict__ wqT, const u16* __restrict__ wkT,
                     const u16* __restrict__ wvT,
                     const float* __restrict__ bq, const float* __restrict__ bk,
                     const float* __restrict__ bv,
                     float* __restrict__ q, float* __restrict__ k, float* __restrict__ v)
{
  int mode = blockIdx.z;
  const u16* BT   = (mode == 0) ? wqT : (mode == 1) ? wkT : wvT;
  const float* bia = (mode == 0) ? bq : (mode == 1) ? bk : bv;
  float* dst       = (mode == 0) ? q : (mode == 1) ? k : v;
  int m0 = blockIdx.x * 128, n0 = blockIdx.y * 128;
  __shared__ __align__(16) u16 As[128 * 64];
  __shared__ __align__(16) u16 Bs[128 * 64];
  int tid = threadIdx.x;
  f32x4 acc[4][4];
#pragma unroll
  for (int i = 0; i < 4; ++i)
#pragma unroll
    for (int j = 0; j < 4; ++j) acc[i][j] = (f32x4){0.f, 0.f, 0.f, 0.f};
  int w = tid >> 6, l = tid & 63;
  int lr = l & 15, lq = l >> 4;
  int wm = (w & 1) * 64, wn = (w >> 1) * 64;
  for (int k0 = 0; k0 < HDIM; k0 += 64) {
#pragma unroll
    for (int p = 0; p < 4; ++p) {
      int flat = p * 256 + tid;
      int r = flat >> 3, c = flat & 7;
      uint4 a4 = *(const uint4*)&xbf[(size_t)(m0 + r) * HDIM + k0 + c * 8];
      *(uint4*)&As[(r * 8 + (c ^ (r & 7))) * 8] = a4;
      uint4 b4 = *(const uint4*)&BT[(size_t)(n0 + r) * HDIM + k0 + c * 8];
      *(uint4*)&Bs[(r * 8 + (c ^ (r & 7))) * 8] = b4;
    }
    __syncthreads();
#pragma unroll
    for (int s = 0; s < 2; ++s) {
      bf16x8 af[4], bfv[4];
#pragma unroll
      for (int i = 0; i < 4; ++i) {
        int mloc = wm + i * 16 + lr;
        af[i]  = *(const bf16x8*)&As[(mloc * 8 + ((s * 4 + lq) ^ (mloc & 7))) * 8];
        int n = wn + i * 16 + lr;
        bfv[i] = *(const bf16x8*)&Bs[(n * 8 + ((s * 4 + lq) ^ (n & 7))) * 8];
      }
#pragma unroll
      for (int i = 0; i < 4; ++i)
#pragma unroll
        for (int j = 0; j < 4; ++j)
          acc[i][j] = __builtin_amdgcn_mfma_f32_16x16x32_bf16(af[i], bfv[j], acc[i][j], 0, 0, 0);
    }
    __syncthreads();
  }
#pragma unroll
  for (int i = 0; i < 4; ++i)
#pragma unroll
    for (int j = 0; j < 4; ++j) {
      int col = n0 + wn + j * 16 + lr;
      float bb = bia[col];
      int hh = col >> 6, d = col & 63;
#pragma unroll
      for (int r = 0; r < 4; ++r) {
        int tg = m0 + wm + i * 16 + lq * 4 + r;
        int bi = tg >> 10, s = tg & 1023;
        dst[((size_t)(bi * NHEAD + hh) * SQL + s) * HEADD + d] = acc[i][j][r] + bb;
      }
    }
}

// ---------------- O-projection: bf16 MFMA, out fp32 [NTOK][HDIM] + bias ----------------
__global__ __launch_bounds__(256)
void proj_mfma_kernel(const u16* __restrict__ aobf, const u16* __restrict__ owT,
                      const float* __restrict__ ob, float* __restrict__ out)
{
  int m0 = blockIdx.x * 128, n0 = blockIdx.y * 128;
  __shared__ __align__(16) u16 As[128 * 64];
  __shared__ __align__(16) u16 Bs[128 * 64];
  int tid = threadIdx.x;
  f32x4 acc[4][4];
#pragma unroll
  for (int i = 0; i < 4; ++i)
#pragma unroll
    for (int j = 0; j < 4; ++j) acc[i][j] = (f32x4){0.f, 0.f, 0.f, 0.f};
  int w = tid >> 6, l = tid & 63;
  int lr = l & 15, lq = l >> 4;
  int wm = (w & 1) * 64, wn = (w >> 1) * 64;
  for (int k0 = 0; k0 < HDIM; k0 += 64) {
#pragma unroll
    for (int p = 0; p < 4; ++p) {
      int flat = p * 256 + tid;
      int r = flat >> 3, c = flat & 7;
      uint4 a4 = *(const uint4*)&aobf[(size_t)(m0 + r) * HDIM + k0 + c * 8];
      *(uint4*)&As[(r * 8 + (c ^ (r & 7))) * 8] = a4;
      uint4 b4 = *(const uint4*)&owT[(size_t)(n0 + r) * HDIM + k0 + c * 8];
      *(uint4*)&Bs[(r * 8 + (c ^ (r & 7))) * 8] = b4;
    }
    __syncthreads();
#pragma unroll
    for (int s = 0; s < 2; ++s) {
      bf16x8 af[4], bfv[4];
#pragma unroll
      for (int i = 0; i < 4; ++i) {
        int mloc = wm + i * 16 + lr;
        af[i]  = *(const bf16x8*)&As[(mloc * 8 + ((s * 4 + lq) ^ (mloc & 7))) * 8];
        int n = wn + i * 16 + lr;
        bfv[i] = *(const bf16x8*)&Bs[(n * 8 + ((s * 4 + lq) ^ (n & 7))) * 8];
      }
#pragma unroll
      for (int i = 0; i < 4; ++i)
#pragma unroll
        for (int j = 0; j < 4; ++j)
          acc[i][j] = __builtin_amdgcn_mfma_f32_16x16x32_bf16(af[i], bfv[j], acc[i][j], 0, 0, 0);
    }
    __syncthreads();
  }
#pragma unroll
  for (int i = 0; i < 4; ++i)
#pragma unroll
    for (int j = 0; j < 4; ++j) {
      int col = n0 + wn + j * 16 + lr;
      float bb = ob[col];
#pragma unroll
      for (int r = 0; r < 4; ++r) {
        int tg = m0 + wm + i * 16 + lq * 4 + r;
        out[(size_t)tg * HDIM + col] = acc[i][j][r] + bb;
      }
    }
}

// ---------------- flash attention, fp32, 64-query tile per block ----------------
// LDS: Qs[d][q], KPs[d][k] (reused as P^T[k][q]), Vs[k][d]; online softmax.
// Output written as bf16 [tok][H] (only consumer is the bf16 MFMA O-projection).
__global__ __launch_bounds__(256)
void attn_kernel(const float* __restrict__ q, const float* __restrict__ k,
                 const float* __restrict__ v, u16* __restrict__ ao)
{
  __shared__ float Qs[64 * 68];
  __shared__ float KPs[64 * 68];
  __shared__ float Vs[64 * 68];
  int id = blockIdx.x;
  int qt = id & 15, bh = id >> 4;     // qt varies fastest -> XCD/work mix
  int q0 = qt * 64;
  int tid = threadIdx.x;
  int tx = tid & 15, ty = tid >> 4;
  const float* qb = q + ((size_t)bh * SQL + q0) * HEADD;
#pragma unroll
  for (int p = 0; p < 4; ++p) {
    int flat = p * 256 + tid;
    int r = flat >> 4, c4 = (flat & 15) * 4;
    float4 t = *(const float4*)&qb[r * HEADD + c4];
    Qs[(c4 + 0) * 68 + r] = t.x;
    Qs[(c4 + 1) * 68 + r] = t.y;
    Qs[(c4 + 2) * 68 + r] = t.z;
    Qs[(c4 + 3) * 68 + r] = t.w;
  }
  float m[4], lsum[4], O[4][4];
#pragma unroll
  for (int i = 0; i < 4; ++i) {
    m[i] = -1e30f; lsum[i] = 0.f;
#pragma unroll
    for (int j = 0; j < 4; ++j) O[i][j] = 0.f;
  }
  for (int kb = 0; kb <= q0; kb += 64) {
    __syncthreads();                    // prev PV done; Qs visible on first iter
    const float* kbp = k + ((size_t)bh * SQL + kb) * HEADD;
    const float* vbp = v + ((size_t)bh * SQL + kb) * HEADD;
#pragma unroll
    for (int p = 0; p < 4; ++p) {
      int flat = p * 256 + tid;
      int r = flat >> 4, c4 = (flat & 15) * 4;
      float4 t = *(const float4*)&kbp[r * HEADD + c4];
      KPs[(c4 + 0) * 68 + r] = t.x;
      KPs[(c4 + 1) * 68 + r] = t.y;
      KPs[(c4 + 2) * 68 + r] = t.z;
      KPs[(c4 + 3) * 68 + r] = t.w;
      float4 tv = *(const float4*)&vbp[r * HEADD + c4];
      *(float4*)&Vs[r * 68 + c4] = tv;
    }
    __syncthreads();
    float sacc[4][4];
#pragma unroll
    for (int i = 0; i < 4; ++i)
#pragma unroll
      for (int j = 0; j < 4; ++j) sacc[i][j] = 0.f;
#pragma unroll 4
    for (int kk = 0; kk < 64; ++kk) {
      float a[4], b[4];
      *(float4*)a = *(const float4*)&Qs[kk * 68 + ty * 4];
      *(float4*)b = *(const float4*)&KPs[kk * 68 + tx * 4];
#pragma unroll
      for (int i = 0; i < 4; ++i)
#pragma unroll
        for (int j = 0; j < 4; ++j)
          sacc[i][j] = fmaf(a[i], b[j], sacc[i][j]);
    }
    __syncthreads();                    // all waves done reading KPs
    float pfrag[4][4];
#pragma unroll
    for (int i = 0; i < 4; ++i) {
      int srow = q0 + ty * 4 + i;
      float sv[4], rm = -1e30f;
#pragma unroll
      for (int j = 0; j < 4; ++j) {
        int col = kb + tx * 4 + j;
        sv[j] = (col <= srow) ? sacc[i][j] * ATT_SCALE : -1e30f;
        rm = fmaxf(rm, sv[j]);
      }
#pragma unroll
      for (int off = 8; off > 0; off >>= 1) rm = fmaxf(rm, __shfl_xor(rm, off));
      float mnew = fmaxf(m[i], rm);
      float alpha = expf(m[i] - mnew);
      float rl = 0.f;
#pragma unroll
      for (int j = 0; j < 4; ++j) {
        float pv = (sv[j] > -1e29f) ? expf(sv[j] - mnew) : 0.f;
        pfrag[i][j] = pv; rl += pv;
      }
#pragma unroll
      for (int off = 8; off > 0; off >>= 1) rl += __shfl_xor(rl, off);
      lsum[i] = lsum[i] * alpha + rl;
      m[i] = mnew;
#pragma unroll
      for (int j = 0; j < 4; ++j) O[i][j] *= alpha;
    }
    // P^T into KPs: [k][q]
#pragma unroll
    for (int i = 0; i < 4; ++i)
#pragma unroll
      for (int j = 0; j < 4; ++j)
        KPs[(tx * 4 + j) * 68 + ty * 4 + i] = pfrag[i][j];
    __syncthreads();
#pragma unroll 4
    for (int kk = 0; kk < 64; ++kk) {
      float a[4], b[4];
      *(float4*)a = *(const float4*)&KPs[kk * 68 + ty * 4];
      *(float4*)b = *(const float4*)&Vs[kk * 68 + tx * 4];
#pragma unroll
      for (int i = 0; i < 4; ++i)
#pragma unroll
        for (int j = 0; j < 4; ++j)
          O[i][j] = fmaf(a[i], b[j], O[i][j]);
    }
  }
  int b = bh >> 4, hh = bh & 15;
#pragma unroll
  for (int i = 0; i < 4; ++i) {
    float invl = 1.0f / lsum[i];
    int srow = q0 + ty * 4 + i;
    ushort4 o = {f2bf(O[i][0] * invl), f2bf(O[i][1] * invl),
                 f2bf(O[i][2] * invl), f2bf(O[i][3] * invl)};
    *(ushort4*)&ao[((size_t)(b * SQL + srow)) * HDIM + hh * HEADD + tx * 4] = o;
  }
}

// ---------------- residual + RMSNorm (fp32 h out + bf16 copy) ----------------
__global__ __launch_bounds__(256)
void rmsnorm_kernel(const float* __restrict__ x, const float* __restrict__ p,
                    const float* __restrict__ w, float* __restrict__ out,
                    u16* __restrict__ outbf)
{
  int t = blockIdx.x, tid = threadIdx.x;
  float4 xv = ((const float4*)(x + (size_t)t * HDIM))[tid];
  float4 pv = ((const float4*)(p + (size_t)t * HDIM))[tid];
  float4 s = {xv.x + pv.x, xv.y + pv.y, xv.z + pv.z, xv.w + pv.w};
  float ss = s.x * s.x + s.y * s.y + s.z * s.z + s.w * s.w;
  __shared__ float red[4];
  float wsv = wave_sum(ss);
  int wid = tid >> 6, l = tid & 63;
  if (l == 0) red[wid] = wsv;
  __syncthreads();
  float tot = red[0] + red[1] + red[2] + red[3];
  float inv = 1.0f / sqrtf(tot / (float)HDIM + 1e-6f);
  float4 wv = ((const float4*)w)[tid];
  float4 o = {s.x * inv * wv.x, s.y * inv * wv.y, s.z * inv * wv.z, s.w * inv * wv.w};
  ((float4*)(out + (size_t)t * HDIM))[tid] = o;
  ushort4 ob = {f2bf(o.x), f2bf(o.y), f2bf(o.z), f2bf(o.w)};
  ((ushort4*)(outbf + (size_t)t * HDIM))[tid] = ob;
}

// ---------------- router: logits, softmax, top-2, weight norm ----------------
__global__ __launch_bounds__(256)
void router_kernel(const float* __restrict__ h, const float* __restrict__ gw,
                   int* __restrict__ ti, float* __restrict__ tw)
{
  int wid = threadIdx.x >> 6, l = threadIdx.x & 63;
  int t = blockIdx.x * 4 + wid;
  const float* hr = h + (size_t)t * HDIM;
  float hv[16];
#pragma unroll
  for (int j = 0; j < 16; ++j) hv[j] = hr[l + 64 * j];
  float lg[NEXP];
#pragma unroll
  for (int e = 0; e < NEXP; ++e) {
    const float* g = gw + (size_t)e * HDIM;
    float p = 0.f;
#pragma unroll
    for (int j = 0; j < 16; ++j) p += hv[j] * g[l + 64 * j];
    lg[e] = wave_sum(p);
  }
  if (l == 0) {
    int i1 = 0; float m1 = lg[0];
#pragma unroll
    for (int e = 1; e < NEXP; ++e) if (lg[e] > m1) { m1 = lg[e]; i1 = e; }
    int i2 = 0; float m2 = -1e30f;
#pragma unroll
    for (int e = 0; e < NEXP; ++e) if (e != i1 && lg[e] > m2) { m2 = lg[e]; i2 = e; }
    float se = 0.f;
#pragma unroll
    for (int e = 0; e < NEXP; ++e) se += expf(lg[e] - m1);
    float p1 = 1.0f / se;
    float p2 = expf(m2 - m1) / se;
    float denom = p1 + p2 + 1e-20f;
    tw[t * 2]     = p1 / denom * 0.5f;
    tw[t * 2 + 1] = p2 / denom * 0.5f;
    ti[t * 2]     = i1;
    ti[t * 2 + 1] = i2;
  }
}

// ---------------- deterministic capacity scan + packed-row bases ----------------
__global__ void scan_kernel(const int* __restrict__ ti, int* __restrict__ eidx,
                            int* __restrict__ counts, int* __restrict__ slotmap,
                            int* __restrict__ ebase)
{
  int l = threadIdx.x;
  int base[NEXP] = {0, 0, 0, 0, 0, 0, 0, 0};
  unsigned long long below = (l == 0) ? 0ull : ((~0ull) >> (64 - l));
  for (int c2 = 0; c2 < (NTOK * 2) / 64; ++c2) {
    int f = c2 * 64 + l;
    int e = ti[f];
    int mypos = 0;
#pragma unroll
    for (int e0 = 0; e0 < NEXP; ++e0) {
      unsigned long long mm = __ballot(e == e0);
      if (e == e0) mypos = base[e0] + __popcll(mm & below);
      base[e0] += __popcll(mm);
    }
    int slot;
    if (mypos < CAPACITY) {
      slot = e * CAPACITY + mypos;
      eidx[slot] = f >> 1;
    } else slot = -1;
    slotmap[f] = slot;
  }
  int eb[NEXP]; int run = 0;
#pragma unroll
  for (int e = 0; e < NEXP; ++e) {
    eb[e] = run;
    run += (base[e] < CAPACITY) ? base[e] : CAPACITY;
  }
  if (l < NEXP) {
    counts[l] = (base[l] < CAPACITY) ? base[l] : CAPACITY;
    ebase[l] = eb[l];
  }
  for (int c2 = 0; c2 < (NTOK * 2) / 64; ++c2) {
    int f = c2 * 64 + l;
    int vv = slotmap[f];
    if (vv >= 0) slotmap[f] = eb[vv >> 11] + (vv & (CAPACITY - 1));
  }
}

// ---------------- MoE GEMM1: gathered hbf @ w1T[e] + b1 -> gelu -> h1 (packed rows) ------
__global__ __launch_bounds__(256)
void moe_gemm1_kernel(const u16* __restrict__ hbf, const u16* __restrict__ w1T,
                      const float* __restrict__ b1, const int* __restrict__ eidx,
                      const int* __restrict__ counts, const int* __restrict__ ebase,
                      u16* __restrict__ h1)
{
  int e = blockIdx.z;
  int cnt = counts[e];
  int m0 = blockIdx.x * 128;
  if (m0 >= cnt) return;
  int n0 = blockIdx.y * 128;
  int base = ebase[e];
  __shared__ __align__(16) u16 As[128 * 64];
  __shared__ __align__(16) u16 Bs[128 * 64];
  __shared__ int rowtok[128];
  int tid = threadIdx.x;
  if (tid < 128) {
    int r = m0 + tid;
    rowtok[tid] = (r < cnt) ? eidx[e * CAPACITY + r] : -1;
  }
  __syncthreads();
  const u16* BT = w1T + (size_t)e * IDIM * HDIM;
  f32x4 acc[4][4];
#pragma unroll
  for (int i = 0; i < 4; ++i)
#pragma unroll
    for (int j = 0; j < 4; ++j) acc[i][j] = (f32x4){0.f, 0.f, 0.f, 0.f};
  int w = tid >> 6, l = tid & 63;
  int lr = l & 15, lq = l >> 4;
  int wm = (w & 1) * 64, wn = (w >> 1) * 64;
  for (int k0 = 0; k0 < HDIM; k0 += 64) {
#pragma unroll
    for (int p = 0; p < 4; ++p) {
      int flat = p * 256 + tid;
      int r = flat >> 3, c = flat & 7;
      int tok = rowtok[r];
      uint4 a4 = {0u, 0u, 0u, 0u};
      if (tok >= 0) a4 = *(const uint4*)&hbf[(size_t)tok * HDIM + k0 + c * 8];
      *(uint4*)&As[(r * 8 + (c ^ (r & 7))) * 8] = a4;
      uint4 b4 = *(const uint4*)&BT[(size_t)(n0 + r) * HDIM + k0 + c * 8];
      *(uint4*)&Bs[(r * 8 + (c ^ (r & 7))) * 8] = b4;
    }
    __syncthreads();
#pragma unroll
    for (int s = 0; s < 2; ++s) {
      bf16x8 af[4], bfv[4];
#pragma unroll
      for (int i = 0; i < 4; ++i) {
        int mloc = wm + i * 16 + lr;
        af[i]  = *(const bf16x8*)&As[(mloc * 8 + ((s * 4 + lq) ^ (mloc & 7))) * 8];
        int n = wn + i * 16 + lr;
        bfv[i] = *(const bf16x8*)&Bs[(n * 8 + ((s * 4 + lq) ^ (n & 7))) * 8];
      }
#pragma unroll
      for (int i = 0; i < 4; ++i)
#pragma unroll
        for (int j = 0; j < 4; ++j)
          acc[i][j] = __builtin_amdgcn_mfma_f32_16x16x32_bf16(af[i], bfv[j], acc[i][j], 0, 0, 0);
    }
    __syncthreads();
  }
#pragma unroll
  for (int i = 0; i < 4; ++i)
#pragma unroll
    for (int j = 0; j < 4; ++j) {
      int col = n0 + wn + j * 16 + lr;
      float bb = b1[(size_t)e * IDIM + col];
#pragma unroll
      for (int r = 0; r < 4; ++r) {
        int rowl = m0 + wm + i * 16 + lq * 4 + r;
        if (rowl < cnt) {
          float y = acc[i][j][r] + bb;
          float g = 0.5f * y * (1.0f + erff(y * 0.70710678118654752f));
          h1[(size_t)(base + rowl) * IDIM + col] = f2bf(g);
        }
      }
    }
}

// ---------------- MoE GEMM2: h1 @ w2T[e] + b2 -> ybuf (packed rows) ----------------
__global__ __launch_bounds__(256)
void moe_gemm2_kernel(const u16* __restrict__ h1, const u16* __restrict__ w2T,
                      const float* __restrict__ b2, const int* __restrict__ counts,
                      const int* __restrict__ ebase, u16* __restrict__ ybuf)
{
  int e = blockIdx.z;
  int cnt = counts[e];
  int m0 = blockIdx.x * 128;
  if (m0 >= cnt) return;
  int n0 = blockIdx.y * 128;
  int base = ebase[e];
  __shared__ __align__(16) u16 As[128 * 64];
  __shared__ __align__(16) u16 Bs[128 * 64];
  int tid = threadIdx.x;
  const u16* BT = w2T + (size_t)e * HDIM * IDIM;
  f32x4 acc[4][4];
#pragma unroll
  for (int i = 0; i < 4; ++i)
#pragma unroll
    for (int j = 0; j < 4; ++j) acc[i][j] = (f32x4){0.f, 0.f, 0.f, 0.f};
  int w = tid >> 6, l = tid & 63;
  int lr = l & 15, lq = l >> 4;
  int wm = (w & 1) * 64, wn = (w >> 1) * 64;
  for (int k0 = 0; k0 < IDIM; k0 += 64) {
#pragma unroll
    for (int p = 0; p < 4; ++p) {
      int flat = p * 256 + tid;
      int r = flat >> 3, c = flat & 7;
      int rowg = m0 + r;
      uint4 a4 = {0u, 0u, 0u, 0u};
      if (rowg < cnt) a4 = *(const uint4*)&h1[(size_t)(base + rowg) * IDIM + k0 + c * 8];
      *(uint4*)&As[(r * 8 + (c ^ (r & 7))) * 8] = a4;
      uint4 b4 = *(const uint4*)&BT[(size_t)(n0 + r) * IDIM + k0 + c * 8];
      *(uint4*)&Bs[(r * 8 + (c ^ (r & 7))) * 8] = b4;
    }
    __syncthreads();
#pragma unroll
    for (int s = 0; s < 2; ++s) {
      bf16x8 af[4], bfv[4];
#pragma unroll
      for (int i = 0; i < 4; ++i) {
        int mloc = wm + i * 16 + lr;
        af[i]  = *(const bf16x8*)&As[(mloc * 8 + ((s * 4 + lq) ^ (mloc & 7))) * 8];
        int n = wn + i * 16 + lr;
        bfv[i] = *(const bf16x8*)&Bs[(n * 8 + ((s * 4 + lq) ^ (n & 7))) * 8];
      }
#pragma unroll
      for (int i = 0; i < 4; ++i)
#pragma unroll
        for (int j = 0; j < 4; ++j)
          acc[i][j] = __builtin_amdgcn_mfma_f32_16x16x32_bf16(af[i], bfv[j], acc[i][j], 0, 0, 0);
    }
    __syncthreads();
  }
#pragma unroll
  for (int i = 0; i < 4; ++i)
#pragma unroll
    for (int j = 0; j < 4; ++j) {
      int col = n0 + wn + j * 16 + lr;
      float bb = b2[(size_t)e * HDIM + col];
#pragma unroll
      for (int r = 0; r < 4; ++r) {
        int rowl = m0 + wm + i * 16 + lq * 4 + r;
        if (rowl < cnt)
          ybuf[(size_t)(base + rowl) * HDIM + col] = f2bf(acc[i][j][r] + bb);
      }
    }
}

// ---------------- final: h + sum_k tw_k * y[row_k] -> LayerNorm -> fp32 out ----------------
__global__ __launch_bounds__(256)
void final_kernel(const float* __restrict__ h, const u16* __restrict__ ybuf,
                  const int* __restrict__ slotmap, const float* __restrict__ tw,
                  const float* __restrict__ lnw, const float* __restrict__ lnb,
                  float* __restrict__ out)
{
  int t = blockIdx.x, tid = threadIdx.x;
  int s0 = slotmap[t * 2], s1 = slotmap[t * 2 + 1];
  float w0 = tw[t * 2], w1v = tw[t * 2 + 1];
  float4 hv = ((const float4*)(h + (size_t)t * HDIM))[tid];
  float vals[4] = {hv.x, hv.y, hv.z, hv.w};
  if (s0 >= 0) {
    const u16* yr = ybuf + (size_t)s0 * HDIM + tid * 4;
#pragma unroll
    for (int j = 0; j < 4; ++j) vals[j] += w0 * bf2f(yr[j]);
  }
  if (s1 >= 0) {
    const u16* yr = ybuf + (size_t)s1 * HDIM + tid * 4;
#pragma unroll
    for (int j = 0; j < 4; ++j) vals[j] += w1v * bf2f(yr[j]);
  }
  float s = vals[0] + vals[1] + vals[2] + vals[3];
  float q2 = vals[0] * vals[0] + vals[1] * vals[1] + vals[2] * vals[2] + vals[3] * vals[3];
  __shared__ float reds[4], redq[4];
  float wsv = wave_sum(s), wqv = wave_sum(q2);
  int wid = tid >> 6, l = tid & 63;
  if (l == 0) { reds[wid] = wsv; redq[wid] = wqv; }
  __syncthreads();
  float tot = reds[0] + reds[1] + reds[2] + reds[3];
  float totq = redq[0] + redq[1] + redq[2] + redq[3];
  float mu = tot / 1024.0f;
  float var = totq / 1024.0f - mu * mu;
  float inv = 1.0f / sqrtf(var + 1e-6f);
#pragma unroll
  for (int j = 0; j < 4; ++j) {
    int c = tid * 4 + j;
    out[(size_t)t * HDIM + c] = (vals[j] - mu) * inv * lnw[c] + lnb[c];
  }
}

extern "C" void kernel_launch(void* const* d_in, const int* in_sizes, int n_in,
                              void* d_out, int out_size, void* d_ws, size_t ws_size,
                              hipStream_t stream)
{
  const float* x      = (const float*)d_in[0];
  const float* qw     = (const float*)d_in[2];
  const float* qb     = (const float*)d_in[3];
  const float* kw     = (const float*)d_in[4];
  const float* kb     = (const float*)d_in[5];
  const float* vw     = (const float*)d_in[6];
  const float* vb     = (const float*)d_in[7];
  const float* ow     = (const float*)d_in[8];
  const float* ob     = (const float*)d_in[9];
  const float* rms_w  = (const float*)d_in[10];
  const float* gate_w = (const float*)d_in[11];
  const float* w1     = (const float*)d_in[12];
  const float* b1     = (const float*)d_in[13];
  const float* w2     = (const float*)d_in[14];
  const float* b2     = (const float*)d_in[15];
  const float* ln_w   = (const float*)d_in[16];
  const float* ln_b   = (const float*)d_in[17];

  char* ws = (char*)d_ws;
  const size_t MB = 1024ull * 1024ull;
  float* qbuf   = (float*)(ws + 0 * MB);    // 16MB fp32 q [bh][s][d]
  float* kbuf   = (float*)(ws + 16 * MB);   // 16MB
  float* vbuf   = (float*)(ws + 32 * MB);   // 16MB
  u16*   aobf   = (u16*)(ws + 48 * MB);     // 8MB bf16 attn-out [tok][H]
  u16*   xbf    = (u16*)(ws + 56 * MB);     // 8MB bf16 x
  u16*   wqT    = (u16*)(ws + 64 * MB);     // 2MB bf16 qw^T  (dead before hbf write)
  u16*   wkT    = (u16*)(ws + 66 * MB);     // 2MB
  u16*   wvT    = (u16*)(ws + 68 * MB);     // 2MB
  u16*   owT    = (u16*)(ws + 70 * MB);     // 2MB
  u16*   wT     = (u16*)(ws + 16 * MB);     // MoE weight^T staging (after attn)
  float* hbuf   = (float*)(ws + 48 * MB);   // 16MB fp32 h (after proj)
  u16*   hbf    = (u16*)(ws + 64 * MB);     // 8MB bf16 h
  u16*   h1buf  = (u16*)(ws + 72 * MB);     // 32MB
  u16*   ybuf   = (u16*)(ws + 104 * MB);    // 16MB
  char*  sm     = ws + 120 * MB;
  int*   ti      = (int*)(sm);
  float* tw      = (float*)(sm + 32 * 1024);
  int*   eidx    = (int*)(sm + 64 * 1024);
  int*   slotmap = (int*)(sm + 128 * 1024);
  int*   counts  = (int*)(sm + 160 * 1024);
  int*   ebase   = (int*)(sm + 164 * 1024);
  float* projbuf = qbuf;

  cvt_bf16_kernel<<<NTOK, 256, 0, stream>>>(x, xbf);
  transpose_cvt_kernel<<<dim3(32, 32, 1), 256, 0, stream>>>(qw, wqT, HDIM, HDIM);
  transpose_cvt_kernel<<<dim3(32, 32, 1), 256, 0, stream>>>(kw, wkT, HDIM, HDIM);
  transpose_cvt_kernel<<<dim3(32, 32, 1), 256, 0, stream>>>(vw, wvT, HDIM, HDIM);
  transpose_cvt_kernel<<<dim3(32, 32, 1), 256, 0, stream>>>(ow, owT, HDIM, HDIM);
  qkv_mfma_kernel<<<dim3(NTOK / 128, HDIM / 128, 3), 256, 0, stream>>>(
      xbf, wqT, wkT, wvT, qb, kb, vb, qbuf, kbuf, vbuf);
  attn_kernel<<<NB * NHEAD * (SQL / 64), 256, 0, stream>>>(qbuf, kbuf, vbuf, aobf);
  proj_mfma_kernel<<<dim3(NTOK / 128, HDIM / 128), 256, 0, stream>>>(
      aobf, owT, ob, projbuf);
  rmsnorm_kernel<<<NTOK, 256, 0, stream>>>(x, projbuf, rms_w, hbuf, hbf);
  transpose_cvt_kernel<<<dim3(IDIM / 32, HDIM / 32, NEXP), 256, 0, stream>>>(
      w1, wT, HDIM, IDIM);
  router_kernel<<<NTOK / 4, 256, 0, stream>>>(hbuf, gate_w, ti, tw);
  scan_kernel<<<1, 64, 0, stream>>>(ti, eidx, counts, slotmap, ebase);
  moe_gemm1_kernel<<<dim3(CAPACITY / 128, IDIM / 128, NEXP), 256, 0, stream>>>(
      hbf, wT, b1, eidx, counts, ebase, h1buf);
  transpose_cvt_kernel<<<dim3(HDIM / 32, IDIM / 32, NEXP), 256, 0, stream>>>(
      w2, wT, IDIM, HDIM);
  moe_gemm2_kernel<<<dim3(CAPACITY / 128, HDIM / 128, NEXP), 256, 0, stream>>>(
      h1buf, wT, b2, counts, ebase, ybuf);
  final_kernel<<<NTOK, 256, 0, stream>>>(hbuf, ybuf, slotmap, tw, ln_w, ln_b,
                                         (float*)d_out);
}

// Round 2
// 799.637 us; speedup vs baseline: 1.7406x; 1.2905x over previous
//
#include <hip/hip_runtime.h>

#define NB 4
#define SQL 1024
#define HDIM 1024
#define NHEAD 16
#define HEADD 64
#define NEXP 8
#define IDIM 2048
#define NTOK (NB*SQL)
#define CAPACITY 2048
#define ATT_SCALE 0.125f

typedef unsigned short u16;
typedef __attribute__((ext_vector_type(8))) short bf16x8;
typedef __attribute__((ext_vector_type(8))) unsigned short u16x8;
typedef __attribute__((ext_vector_type(4))) float f32x4;

__device__ __forceinline__ u16 f2bf(float f) {
  union { float f; unsigned u; } x; x.f = f;
  unsigned r = (x.u + 0x7fffu + ((x.u >> 16) & 1u)) >> 16;
  return (u16)r;
}
__device__ __forceinline__ float bf2f(u16 b) {
  union { unsigned u; float f; } x; x.u = ((unsigned)b) << 16;
  return x.f;
}
__device__ __forceinline__ float wave_sum(float v) {
#pragma unroll
  for (int off = 32; off > 0; off >>= 1) v += __shfl_xor(v, off);
  return v;
}

// ---------------- fp32 -> bf16 row convert (x) ----------------
__global__ __launch_bounds__(256)
void cvt_bf16_kernel(const float* __restrict__ in, u16* __restrict__ out)
{
  size_t i = (size_t)blockIdx.x * 1024 + threadIdx.x * 4;
  float4 v = *(const float4*)&in[i];
  ushort4 o = {f2bf(v.x), f2bf(v.y), f2bf(v.z), f2bf(v.w)};
  *(ushort4*)&out[i] = o;
}

// ---------------- transpose+convert: in fp32 [e][R][C] -> out bf16 [e][C][R] ----------------
__global__ __launch_bounds__(256)
void transpose_cvt_kernel(const float* __restrict__ in, u16* __restrict__ out,
                          int R, int C)
{
  int e = blockIdx.z;
  const float* ine = in + (size_t)e * R * C;
  u16* oute = out + (size_t)e * R * C;
  __shared__ u16 Ts[32 * 34];
  int tx = threadIdx.x & 31, ty = threadIdx.x >> 5;
  int r0 = blockIdx.y * 32, c0 = blockIdx.x * 32;
#pragma unroll
  for (int qq = 0; qq < 4; ++qq) {
    int rr = ty + qq * 8;
    Ts[tx * 34 + rr] = f2bf(ine[(size_t)(r0 + rr) * C + c0 + tx]);
  }
  __syncthreads();
#pragma unroll
  for (int qq = 0; qq < 4; ++qq) {
    int cc = ty + qq * 8;
    oute[(size_t)(c0 + cc) * R + r0 + tx] = Ts[cc * 34 + tx];
  }
}

// ---------------- QKV projection: bf16 MFMA 128x128 tile, K=HDIM ----------------
// A = xbf [NTOK][HDIM] bf16; B = W^T [HDIM(out)][HDIM(in)] bf16; out bf16 scattered
// into q/k/v [B*NH][S][HD] with bias.
__global__ __launch_bounds__(256)
void qkv_mfma_kernel(const u16* __restrict__ xbf,
                     const u16* __restrict__ wqT, const u16* __restrict__ wkT,
                     const u16* __restrict__ wvT,
                     const float* __restrict__ bq, const float* __restrict__ bk,
                     const float* __restrict__ bv,
                     u16* __restrict__ q, u16* __restrict__ k, u16* __restrict__ v)
{
  int mode = blockIdx.z;
  const u16* BT   = (mode == 0) ? wqT : (mode == 1) ? wkT : wvT;
  const float* bia = (mode == 0) ? bq : (mode == 1) ? bk : bv;
  u16* dst         = (mode == 0) ? q : (mode == 1) ? k : v;
  int m0 = blockIdx.x * 128, n0 = blockIdx.y * 128;
  __shared__ __align__(16) u16 As[128 * 64];
  __shared__ __align__(16) u16 Bs[128 * 64];
  int tid = threadIdx.x;
  f32x4 acc[4][4];
#pragma unroll
  for (int i = 0; i < 4; ++i)
#pragma unroll
    for (int j = 0; j < 4; ++j) acc[i][j] = (f32x4){0.f, 0.f, 0.f, 0.f};
  int w = tid >> 6, l = tid & 63;
  int lr = l & 15, lq = l >> 4;
  int wm = (w & 1) * 64, wn = (w >> 1) * 64;
  for (int k0 = 0; k0 < HDIM; k0 += 64) {
#pragma unroll
    for (int p = 0; p < 4; ++p) {
      int flat = p * 256 + tid;
      int r = flat >> 3, c = flat & 7;
      uint4 a4 = *(const uint4*)&xbf[(size_t)(m0 + r) * HDIM + k0 + c * 8];
      *(uint4*)&As[(r * 8 + (c ^ (r & 7))) * 8] = a4;
      uint4 b4 = *(const uint4*)&BT[(size_t)(n0 + r) * HDIM + k0 + c * 8];
      *(uint4*)&Bs[(r * 8 + (c ^ (r & 7))) * 8] = b4;
    }
    __syncthreads();
#pragma unroll
    for (int s = 0; s < 2; ++s) {
      bf16x8 af[4], bfv[4];
#pragma unroll
      for (int i = 0; i < 4; ++i) {
        int mloc = wm + i * 16 + lr;
        af[i]  = *(const bf16x8*)&As[(mloc * 8 + ((s * 4 + lq) ^ (mloc & 7))) * 8];
        int n = wn + i * 16 + lr;
        bfv[i] = *(const bf16x8*)&Bs[(n * 8 + ((s * 4 + lq) ^ (n & 7))) * 8];
      }
#pragma unroll
      for (int i = 0; i < 4; ++i)
#pragma unroll
        for (int j = 0; j < 4; ++j)
          acc[i][j] = __builtin_amdgcn_mfma_f32_16x16x32_bf16(af[i], bfv[j], acc[i][j], 0, 0, 0);
    }
    __syncthreads();
  }
#pragma unroll
  for (int i = 0; i < 4; ++i)
#pragma unroll
    for (int j = 0; j < 4; ++j) {
      int col = n0 + wn + j * 16 + lr;
      float bb = bia[col];
      int hh = col >> 6, d = col & 63;
#pragma unroll
      for (int r = 0; r < 4; ++r) {
        int tg = m0 + wm + i * 16 + lq * 4 + r;
        int bi = tg >> 10, s = tg & 1023;
        dst[((size_t)(bi * NHEAD + hh) * SQL + s) * HEADD + d] = f2bf(acc[i][j][r] + bb);
      }
    }
}

// ---------------- O-projection: bf16 MFMA, out fp32 [NTOK][HDIM] + bias ----------------
__global__ __launch_bounds__(256)
void proj_mfma_kernel(const u16* __restrict__ aobf, const u16* __restrict__ owT,
                      const float* __restrict__ ob, float* __restrict__ out)
{
  int m0 = blockIdx.x * 128, n0 = blockIdx.y * 128;
  __shared__ __align__(16) u16 As[128 * 64];
  __shared__ __align__(16) u16 Bs[128 * 64];
  int tid = threadIdx.x;
  f32x4 acc[4][4];
#pragma unroll
  for (int i = 0; i < 4; ++i)
#pragma unroll
    for (int j = 0; j < 4; ++j) acc[i][j] = (f32x4){0.f, 0.f, 0.f, 0.f};
  int w = tid >> 6, l = tid & 63;
  int lr = l & 15, lq = l >> 4;
  int wm = (w & 1) * 64, wn = (w >> 1) * 64;
  for (int k0 = 0; k0 < HDIM; k0 += 64) {
#pragma unroll
    for (int p = 0; p < 4; ++p) {
      int flat = p * 256 + tid;
      int r = flat >> 3, c = flat & 7;
      uint4 a4 = *(const uint4*)&aobf[(size_t)(m0 + r) * HDIM + k0 + c * 8];
      *(uint4*)&As[(r * 8 + (c ^ (r & 7))) * 8] = a4;
      uint4 b4 = *(const uint4*)&owT[(size_t)(n0 + r) * HDIM + k0 + c * 8];
      *(uint4*)&Bs[(r * 8 + (c ^ (r & 7))) * 8] = b4;
    }
    __syncthreads();
#pragma unroll
    for (int s = 0; s < 2; ++s) {
      bf16x8 af[4], bfv[4];
#pragma unroll
      for (int i = 0; i < 4; ++i) {
        int mloc = wm + i * 16 + lr;
        af[i]  = *(const bf16x8*)&As[(mloc * 8 + ((s * 4 + lq) ^ (mloc & 7))) * 8];
        int n = wn + i * 16 + lr;
        bfv[i] = *(const bf16x8*)&Bs[(n * 8 + ((s * 4 + lq) ^ (n & 7))) * 8];
      }
#pragma unroll
      for (int i = 0; i < 4; ++i)
#pragma unroll
        for (int j = 0; j < 4; ++j)
          acc[i][j] = __builtin_amdgcn_mfma_f32_16x16x32_bf16(af[i], bfv[j], acc[i][j], 0, 0, 0);
    }
    __syncthreads();
  }
#pragma unroll
  for (int i = 0; i < 4; ++i)
#pragma unroll
    for (int j = 0; j < 4; ++j) {
      int col = n0 + wn + j * 16 + lr;
      float bb = ob[col];
#pragma unroll
      for (int r = 0; r < 4; ++r) {
        int tg = m0 + wm + i * 16 + lq * 4 + r;
        out[(size_t)tg * HDIM + col] = acc[i][j][r] + bb;
      }
    }
}

// ---------------- flash attention, bf16 MFMA ----------------
// Block: one (b,h), 64-query tile, 4 waves x 16 q-rows. KV tiles of 64.
// Q/K fragments direct from global (L2-resident); V^T staged in LDS;
// P re-layout (C->A fragment) through per-wave LDS. Only diagonal tile masks.
// Block order: bid = (15-qt)*64 + bh  => same-bh blocks share bid%8 (XCD L2 pin).
__global__ __launch_bounds__(256)
void attn_mfma_kernel(const u16* __restrict__ q, const u16* __restrict__ k,
                      const u16* __restrict__ v, u16* __restrict__ ao)
{
  __shared__ __align__(16) u16 VT[64 * 72];       // V^T [d][key], stride 72
  __shared__ __align__(16) u16 Pl[4][16 * 72];    // per-wave P [q][key]
  int bid = blockIdx.x;
  int bh = bid & 63;
  int qt = 15 - (bid >> 6);
  int q0 = qt * 64;
  int tid = threadIdx.x;
  int w = tid >> 6, l = tid & 63;
  int lr = l & 15, lq = l >> 4;

  // Q fragments: row = q0 + w*16 + lr, d-slabs of 32, lane holds d = s*32+lq*8..+7
  const u16* qp = q + ((size_t)bh * SQL + q0 + w * 16 + lr) * HEADD + lq * 8;
  bf16x8 qf0 = *(const bf16x8*)qp;
  bf16x8 qf1 = *(const bf16x8*)(qp + 32);

  float mrow[4], lrow[4];
  f32x4 Ot[4];
#pragma unroll
  for (int r = 0; r < 4; ++r) { mrow[r] = -1e30f; lrow[r] = 0.f; }
#pragma unroll
  for (int j = 0; j < 4; ++j) Ot[j] = (f32x4){0.f, 0.f, 0.f, 0.f};

  int vkey = 2 * (l & 31);              // key pair this lane stages
  int vd0 = w * 16 + (l >> 5) * 8;      // 8 d-rows this lane stages

  for (int kb = 0; kb <= q0; kb += 64) {
    __syncthreads();                    // prev-tile VT reads complete
    // ---- stage V^T: [64 key][64 d] -> VT[d][key] ----
    {
      const u16* vp = v + ((size_t)bh * SQL + kb + vkey) * HEADD + vd0;
      u16x8 a = *(const u16x8*)vp;
      u16x8 b = *(const u16x8*)(vp + HEADD);
#pragma unroll
      for (int e = 0; e < 8; ++e) {
        ushort2 pr = {a[e], b[e]};
        *(ushort2*)&VT[(vd0 + e) * 72 + vkey] = pr;
      }
    }
    // ---- QK^T: S[16q x 64k] per wave ----
    f32x4 sacc[4];
#pragma unroll
    for (int j = 0; j < 4; ++j) sacc[j] = (f32x4){0.f, 0.f, 0.f, 0.f};
    const u16* kp = k + ((size_t)bh * SQL + kb + lr) * HEADD + lq * 8;
#pragma unroll
    for (int j = 0; j < 4; ++j) {
      bf16x8 kf0 = *(const bf16x8*)(kp + (size_t)j * 16 * HEADD);
      bf16x8 kf1 = *(const bf16x8*)(kp + (size_t)j * 16 * HEADD + 32);
      sacc[j] = __builtin_amdgcn_mfma_f32_16x16x32_bf16(qf0, kf0, sacc[j], 0, 0, 0);
      sacc[j] = __builtin_amdgcn_mfma_f32_16x16x32_bf16(qf1, kf1, sacc[j], 0, 0, 0);
    }
    // ---- online softmax (rows = lq*4+r, cols = j*16+lr across the 16-lane group) ----
    bool diag = (kb == q0);
    float pv[4][4];
#pragma unroll
    for (int r = 0; r < 4; ++r) {
      float sv[4];
      float rm = -1e30f;
#pragma unroll
      for (int j = 0; j < 4; ++j) {
        float s0 = sacc[j][r] * ATT_SCALE;
        if (diag && (j * 16 + lr) > (w * 16 + lq * 4 + r)) s0 = -1e30f;
        sv[j] = s0;
        rm = fmaxf(rm, s0);
      }
      rm = fmaxf(rm, __shfl_xor(rm, 1));
      rm = fmaxf(rm, __shfl_xor(rm, 2));
      rm = fmaxf(rm, __shfl_xor(rm, 4));
      rm = fmaxf(rm, __shfl_xor(rm, 8));
      float mnew = fmaxf(mrow[r], rm);
      float alpha = __expf(mrow[r] - mnew);
      mrow[r] = mnew;
      float rl = 0.f;
#pragma unroll
      for (int j = 0; j < 4; ++j) {
        float p = __expf(sv[j] - mnew);
        pv[j][r] = p;
        rl += p;
      }
      rl += __shfl_xor(rl, 1);
      rl += __shfl_xor(rl, 2);
      rl += __shfl_xor(rl, 4);
      rl += __shfl_xor(rl, 8);
      lrow[r] = lrow[r] * alpha + rl;
#pragma unroll
      for (int j2 = 0; j2 < 4; ++j2) Ot[j2][r] *= alpha;
    }
    // ---- P -> per-wave LDS (C layout -> memory [q][key]) ----
#pragma unroll
    for (int j = 0; j < 4; ++j)
#pragma unroll
      for (int r = 0; r < 4; ++r)
        Pl[w][(lq * 4 + r) * 72 + j * 16 + lr] = f2bf(pv[j][r]);
    __syncthreads();                    // VT staged (and Pl ordering w/ waitcnt)
    // ---- PV: O[16q x 64d] += P @ V ----
    const u16* pbase = &Pl[w][lr * 72];
#pragma unroll
    for (int s = 0; s < 2; ++s) {
      bf16x8 pa = *(const bf16x8*)(pbase + s * 32 + lq * 8);
#pragma unroll
      for (int j2 = 0; j2 < 4; ++j2) {
        bf16x8 vb = *(const bf16x8*)&VT[(j2 * 16 + lr) * 72 + s * 32 + lq * 8];
        Ot[j2] = __builtin_amdgcn_mfma_f32_16x16x32_bf16(pa, vb, Ot[j2], 0, 0, 0);
      }
    }
  }
  // ---- epilogue: normalize, store bf16 [tok][H] ----
  int b = bh >> 4, hh = bh & 15;
#pragma unroll
  for (int r = 0; r < 4; ++r) {
    float invl = 1.0f / lrow[r];
    int row = q0 + w * 16 + lq * 4 + r;
#pragma unroll
    for (int j2 = 0; j2 < 4; ++j2)
      ao[((size_t)(b * SQL + row)) * HDIM + hh * HEADD + j2 * 16 + lr] =
          f2bf(Ot[j2][r] * invl);
  }
}

// ---------------- residual + RMSNorm (fp32 h out + bf16 copy) ----------------
__global__ __launch_bounds__(256)
void rmsnorm_kernel(const float* __restrict__ x, const float* __restrict__ p,
                    const float* __restrict__ w, float* __restrict__ out,
                    u16* __restrict__ outbf)
{
  int t = blockIdx.x, tid = threadIdx.x;
  float4 xv = ((const float4*)(x + (size_t)t * HDIM))[tid];
  float4 pv = ((const float4*)(p + (size_t)t * HDIM))[tid];
  float4 s = {xv.x + pv.x, xv.y + pv.y, xv.z + pv.z, xv.w + pv.w};
  float ss = s.x * s.x + s.y * s.y + s.z * s.z + s.w * s.w;
  __shared__ float red[4];
  float wsv = wave_sum(ss);
  int wid = tid >> 6, l = tid & 63;
  if (l == 0) red[wid] = wsv;
  __syncthreads();
  float tot = red[0] + red[1] + red[2] + red[3];
  float inv = 1.0f / sqrtf(tot / (float)HDIM + 1e-6f);
  float4 wv = ((const float4*)w)[tid];
  float4 o = {s.x * inv * wv.x, s.y * inv * wv.y, s.z * inv * wv.z, s.w * inv * wv.w};
  ((float4*)(out + (size_t)t * HDIM))[tid] = o;
  ushort4 ob = {f2bf(o.x), f2bf(o.y), f2bf(o.z), f2bf(o.w)};
  ((ushort4*)(outbf + (size_t)t * HDIM))[tid] = ob;
}

// ---------------- router: logits, softmax, top-2, weight norm ----------------
__global__ __launch_bounds__(256)
void router_kernel(const float* __restrict__ h, const float* __restrict__ gw,
                   int* __restrict__ ti, float* __restrict__ tw)
{
  int wid = threadIdx.x >> 6, l = threadIdx.x & 63;
  int t = blockIdx.x * 4 + wid;
  const float* hr = h + (size_t)t * HDIM;
  float hv[16];
#pragma unroll
  for (int j = 0; j < 16; ++j) hv[j] = hr[l + 64 * j];
  float lg[NEXP];
#pragma unroll
  for (int e = 0; e < NEXP; ++e) {
    const float* g = gw + (size_t)e * HDIM;
    float p = 0.f;
#pragma unroll
    for (int j = 0; j < 16; ++j) p += hv[j] * g[l + 64 * j];
    lg[e] = wave_sum(p);
  }
  if (l == 0) {
    int i1 = 0; float m1 = lg[0];
#pragma unroll
    for (int e = 1; e < NEXP; ++e) if (lg[e] > m1) { m1 = lg[e]; i1 = e; }
    int i2 = 0; float m2 = -1e30f;
#pragma unroll
    for (int e = 0; e < NEXP; ++e) if (e != i1 && lg[e] > m2) { m2 = lg[e]; i2 = e; }
    float se = 0.f;
#pragma unroll
    for (int e = 0; e < NEXP; ++e) se += expf(lg[e] - m1);
    float p1 = 1.0f / se;
    float p2 = expf(m2 - m1) / se;
    float denom = p1 + p2 + 1e-20f;
    tw[t * 2]     = p1 / denom * 0.5f;
    tw[t * 2 + 1] = p2 / denom * 0.5f;
    ti[t * 2]     = i1;
    ti[t * 2 + 1] = i2;
  }
}

// ---------------- deterministic capacity scan + packed-row bases ----------------
__global__ void scan_kernel(const int* __restrict__ ti, int* __restrict__ eidx,
                            int* __restrict__ counts, int* __restrict__ slotmap,
                            int* __restrict__ ebase)
{
  int l = threadIdx.x;
  int base[NEXP] = {0, 0, 0, 0, 0, 0, 0, 0};
  unsigned long long below = (l == 0) ? 0ull : ((~0ull) >> (64 - l));
  for (int c2 = 0; c2 < (NTOK * 2) / 64; ++c2) {
    int f = c2 * 64 + l;
    int e = ti[f];
    int mypos = 0;
#pragma unroll
    for (int e0 = 0; e0 < NEXP; ++e0) {
      unsigned long long mm = __ballot(e == e0);
      if (e == e0) mypos = base[e0] + __popcll(mm & below);
      base[e0] += __popcll(mm);
    }
    int slot;
    if (mypos < CAPACITY) {
      slot = e * CAPACITY + mypos;
      eidx[slot] = f >> 1;
    } else slot = -1;
    slotmap[f] = slot;
  }
  int eb[NEXP]; int run = 0;
#pragma unroll
  for (int e = 0; e < NEXP; ++e) {
    eb[e] = run;
    run += (base[e] < CAPACITY) ? base[e] : CAPACITY;
  }
  if (l < NEXP) {
    counts[l] = (base[l] < CAPACITY) ? base[l] : CAPACITY;
    ebase[l] = eb[l];
  }
  for (int c2 = 0; c2 < (NTOK * 2) / 64; ++c2) {
    int f = c2 * 64 + l;
    int vv = slotmap[f];
    if (vv >= 0) slotmap[f] = eb[vv >> 11] + (vv & (CAPACITY - 1));
  }
}

// ---------------- MoE GEMM1: gathered hbf @ w1T[e] + b1 -> gelu -> h1 (packed rows) ------
__global__ __launch_bounds__(256)
void moe_gemm1_kernel(const u16* __restrict__ hbf, const u16* __restrict__ w1T,
                      const float* __restrict__ b1, const int* __restrict__ eidx,
                      const int* __restrict__ counts, const int* __restrict__ ebase,
                      u16* __restrict__ h1)
{
  int e = blockIdx.z;
  int cnt = counts[e];
  int m0 = blockIdx.x * 128;
  if (m0 >= cnt) return;
  int n0 = blockIdx.y * 128;
  int base = ebase[e];
  __shared__ __align__(16) u16 As[128 * 64];
  __shared__ __align__(16) u16 Bs[128 * 64];
  __shared__ int rowtok[128];
  int tid = threadIdx.x;
  if (tid < 128) {
    int r = m0 + tid;
    rowtok[tid] = (r < cnt) ? eidx[e * CAPACITY + r] : -1;
  }
  __syncthreads();
  const u16* BT = w1T + (size_t)e * IDIM * HDIM;
  f32x4 acc[4][4];
#pragma unroll
  for (int i = 0; i < 4; ++i)
#pragma unroll
    for (int j = 0; j < 4; ++j) acc[i][j] = (f32x4){0.f, 0.f, 0.f, 0.f};
  int w = tid >> 6, l = tid & 63;
  int lr = l & 15, lq = l >> 4;
  int wm = (w & 1) * 64, wn = (w >> 1) * 64;
  for (int k0 = 0; k0 < HDIM; k0 += 64) {
#pragma unroll
    for (int p = 0; p < 4; ++p) {
      int flat = p * 256 + tid;
      int r = flat >> 3, c = flat & 7;
      int tok = rowtok[r];
      uint4 a4 = {0u, 0u, 0u, 0u};
      if (tok >= 0) a4 = *(const uint4*)&hbf[(size_t)tok * HDIM + k0 + c * 8];
      *(uint4*)&As[(r * 8 + (c ^ (r & 7))) * 8] = a4;
      uint4 b4 = *(const uint4*)&BT[(size_t)(n0 + r) * HDIM + k0 + c * 8];
      *(uint4*)&Bs[(r * 8 + (c ^ (r & 7))) * 8] = b4;
    }
    __syncthreads();
#pragma unroll
    for (int s = 0; s < 2; ++s) {
      bf16x8 af[4], bfv[4];
#pragma unroll
      for (int i = 0; i < 4; ++i) {
        int mloc = wm + i * 16 + lr;
        af[i]  = *(const bf16x8*)&As[(mloc * 8 + ((s * 4 + lq) ^ (mloc & 7))) * 8];
        int n = wn + i * 16 + lr;
        bfv[i] = *(const bf16x8*)&Bs[(n * 8 + ((s * 4 + lq) ^ (n & 7))) * 8];
      }
#pragma unroll
      for (int i = 0; i < 4; ++i)
#pragma unroll
        for (int j = 0; j < 4; ++j)
          acc[i][j] = __builtin_amdgcn_mfma_f32_16x16x32_bf16(af[i], bfv[j], acc[i][j], 0, 0, 0);
    }
    __syncthreads();
  }
#pragma unroll
  for (int i = 0; i < 4; ++i)
#pragma unroll
    for (int j = 0; j < 4; ++j) {
      int col = n0 + wn + j * 16 + lr;
      float bb = b1[(size_t)e * IDIM + col];
#pragma unroll
      for (int r = 0; r < 4; ++r) {
        int rowl = m0 + wm + i * 16 + lq * 4 + r;
        if (rowl < cnt) {
          float y = acc[i][j][r] + bb;
          float g = 0.5f * y * (1.0f + erff(y * 0.70710678118654752f));
          h1[(size_t)(base + rowl) * IDIM + col] = f2bf(g);
        }
      }
    }
}

// ---------------- MoE GEMM2: h1 @ w2T[e] + b2 -> ybuf (packed rows) ----------------
__global__ __launch_bounds__(256)
void moe_gemm2_kernel(const u16* __restrict__ h1, const u16* __restrict__ w2T,
                      const float* __restrict__ b2, const int* __restrict__ counts,
                      const int* __restrict__ ebase, u16* __restrict__ ybuf)
{
  int e = blockIdx.z;
  int cnt = counts[e];
  int m0 = blockIdx.x * 128;
  if (m0 >= cnt) return;
  int n0 = blockIdx.y * 128;
  int base = ebase[e];
  __shared__ __align__(16) u16 As[128 * 64];
  __shared__ __align__(16) u16 Bs[128 * 64];
  int tid = threadIdx.x;
  const u16* BT = w2T + (size_t)e * HDIM * IDIM;
  f32x4 acc[4][4];
#pragma unroll
  for (int i = 0; i < 4; ++i)
#pragma unroll
    for (int j = 0; j < 4; ++j) acc[i][j] = (f32x4){0.f, 0.f, 0.f, 0.f};
  int w = tid >> 6, l = tid & 63;
  int lr = l & 15, lq = l >> 4;
  int wm = (w & 1) * 64, wn = (w >> 1) * 64;
  for (int k0 = 0; k0 < IDIM; k0 += 64) {
#pragma unroll
    for (int p = 0; p < 4; ++p) {
      int flat = p * 256 + tid;
      int r = flat >> 3, c = flat & 7;
      int rowg = m0 + r;
      uint4 a4 = {0u, 0u, 0u, 0u};
      if (rowg < cnt) a4 = *(const uint4*)&h1[(size_t)(base + rowg) * IDIM + k0 + c * 8];
      *(uint4*)&As[(r * 8 + (c ^ (r & 7))) * 8] = a4;
      uint4 b4 = *(const uint4*)&BT[(size_t)(n0 + r) * IDIM + k0 + c * 8];
      *(uint4*)&Bs[(r * 8 + (c ^ (r & 7))) * 8] = b4;
    }
    __syncthreads();
#pragma unroll
    for (int s = 0; s < 2; ++s) {
      bf16x8 af[4], bfv[4];
#pragma unroll
      for (int i = 0; i < 4; ++i) {
        int mloc = wm + i * 16 + lr;
        af[i]  = *(const bf16x8*)&As[(mloc * 8 + ((s * 4 + lq) ^ (mloc & 7))) * 8];
        int n = wn + i * 16 + lr;
        bfv[i] = *(const bf16x8*)&Bs[(n * 8 + ((s * 4 + lq) ^ (n & 7))) * 8];
      }
#pragma unroll
      for (int i = 0; i < 4; ++i)
#pragma unroll
        for (int j = 0; j < 4; ++j)
          acc[i][j] = __builtin_amdgcn_mfma_f32_16x16x32_bf16(af[i], bfv[j], acc[i][j], 0, 0, 0);
    }
    __syncthreads();
  }
#pragma unroll
  for (int i = 0; i < 4; ++i)
#pragma unroll
    for (int j = 0; j < 4; ++j) {
      int col = n0 + wn + j * 16 + lr;
      float bb = b2[(size_t)e * HDIM + col];
#pragma unroll
      for (int r = 0; r < 4; ++r) {
        int rowl = m0 + wm + i * 16 + lq * 4 + r;
        if (rowl < cnt)
          ybuf[(size_t)(base + rowl) * HDIM + col] = f2bf(acc[i][j][r] + bb);
      }
    }
}

// ---------------- final: h + sum_k tw_k * y[row_k] -> LayerNorm -> fp32 out ----------------
__global__ __launch_bounds__(256)
void final_kernel(const float* __restrict__ h, const u16* __restrict__ ybuf,
                  const int* __restrict__ slotmap, const float* __restrict__ tw,
                  const float* __restrict__ lnw, const float* __restrict__ lnb,
                  float* __restrict__ out)
{
  int t = blockIdx.x, tid = threadIdx.x;
  int s0 = slotmap[t * 2], s1 = slotmap[t * 2 + 1];
  float w0 = tw[t * 2], w1v = tw[t * 2 + 1];
  float4 hv = ((const float4*)(h + (size_t)t * HDIM))[tid];
  float vals[4] = {hv.x, hv.y, hv.z, hv.w};
  if (s0 >= 0) {
    const u16* yr = ybuf + (size_t)s0 * HDIM + tid * 4;
#pragma unroll
    for (int j = 0; j < 4; ++j) vals[j] += w0 * bf2f(yr[j]);
  }
  if (s1 >= 0) {
    const u16* yr = ybuf + (size_t)s1 * HDIM + tid * 4;
#pragma unroll
    for (int j = 0; j < 4; ++j) vals[j] += w1v * bf2f(yr[j]);
  }
  float s = vals[0] + vals[1] + vals[2] + vals[3];
  float q2 = vals[0] * vals[0] + vals[1] * vals[1] + vals[2] * vals[2] + vals[3] * vals[3];
  __shared__ float reds[4], redq[4];
  float wsv = wave_sum(s), wqv = wave_sum(q2);
  int wid = tid >> 6, l = tid & 63;
  if (l == 0) { reds[wid] = wsv; redq[wid] = wqv; }
  __syncthreads();
  float tot = reds[0] + reds[1] + reds[2] + reds[3];
  float totq = redq[0] + redq[1] + redq[2] + redq[3];
  float mu = tot / 1024.0f;
  float var = totq / 1024.0f - mu * mu;
  float inv = 1.0f / sqrtf(var + 1e-6f);
#pragma unroll
  for (int j = 0; j < 4; ++j) {
    int c = tid * 4 + j;
    out[(size_t)t * HDIM + c] = (vals[j] - mu) * inv * lnw[c] + lnb[c];
  }
}

extern "C" void kernel_launch(void* const* d_in, const int* in_sizes, int n_in,
                              void* d_out, int out_size, void* d_ws, size_t ws_size,
                              hipStream_t stream)
{
  const float* x      = (const float*)d_in[0];
  const float* qw     = (const float*)d_in[2];
  const float* qb     = (const float*)d_in[3];
  const float* kw     = (const float*)d_in[4];
  const float* kb     = (const float*)d_in[5];
  const float* vw     = (const float*)d_in[6];
  const float* vb     = (const float*)d_in[7];
  const float* ow     = (const float*)d_in[8];
  const float* ob     = (const float*)d_in[9];
  const float* rms_w  = (const float*)d_in[10];
  const float* gate_w = (const float*)d_in[11];
  const float* w1     = (const float*)d_in[12];
  const float* b1     = (const float*)d_in[13];
  const float* w2     = (const float*)d_in[14];
  const float* b2     = (const float*)d_in[15];
  const float* ln_w   = (const float*)d_in[16];
  const float* ln_b   = (const float*)d_in[17];

  char* ws = (char*)d_ws;
  const size_t MB = 1024ull * 1024ull;
  u16*   qbf    = (u16*)(ws + 0 * MB);     // 8MB bf16 q [bh][s][d]
  u16*   kbf    = (u16*)(ws + 8 * MB);     // 8MB
  u16*   vbf    = (u16*)(ws + 16 * MB);    // 8MB
  u16*   aobf   = (u16*)(ws + 24 * MB);    // 8MB bf16 attn-out [tok][H]
  u16*   xbf    = (u16*)(ws + 32 * MB);    // 8MB bf16 x
  u16*   wqT    = (u16*)(ws + 40 * MB);    // 2MB
  u16*   wkT    = (u16*)(ws + 42 * MB);    // 2MB
  u16*   wvT    = (u16*)(ws + 44 * MB);    // 2MB
  u16*   owT    = (u16*)(ws + 46 * MB);    // 2MB
  float* projbuf= (float*)(ws + 48 * MB);  // 16MB fp32 attn-proj out
  float* hbuf   = (float*)(ws + 64 * MB);  // 16MB fp32 h
  u16*   hbf    = (u16*)(ws + 80 * MB);    // 8MB bf16 h
  u16*   wT     = (u16*)(ws + 0 * MB);     // MoE weight^T staging, 32MB (q/k/v/ao dead)
  u16*   ybuf   = (u16*)(ws + 32 * MB);    // 16MB (xbf + w*T dead)
  u16*   h1buf  = (u16*)(ws + 88 * MB);    // 32MB
  char*  sm     = ws + 120 * MB;
  int*   ti      = (int*)(sm);
  float* tw      = (float*)(sm + 32 * 1024);
  int*   eidx    = (int*)(sm + 64 * 1024);
  int*   slotmap = (int*)(sm + 128 * 1024);
  int*   counts  = (int*)(sm + 160 * 1024);
  int*   ebase   = (int*)(sm + 164 * 1024);

  cvt_bf16_kernel<<<NTOK, 256, 0, stream>>>(x, xbf);
  transpose_cvt_kernel<<<dim3(32, 32, 1), 256, 0, stream>>>(qw, wqT, HDIM, HDIM);
  transpose_cvt_kernel<<<dim3(32, 32, 1), 256, 0, stream>>>(kw, wkT, HDIM, HDIM);
  transpose_cvt_kernel<<<dim3(32, 32, 1), 256, 0, stream>>>(vw, wvT, HDIM, HDIM);
  transpose_cvt_kernel<<<dim3(32, 32, 1), 256, 0, stream>>>(ow, owT, HDIM, HDIM);
  qkv_mfma_kernel<<<dim3(NTOK / 128, HDIM / 128, 3), 256, 0, stream>>>(
      xbf, wqT, wkT, wvT, qb, kb, vb, qbf, kbf, vbf);
  attn_mfma_kernel<<<NB * NHEAD * (SQL / 64), 256, 0, stream>>>(qbf, kbf, vbf, aobf);
  proj_mfma_kernel<<<dim3(NTOK / 128, HDIM / 128), 256, 0, stream>>>(
      aobf, owT, ob, projbuf);
  rmsnorm_kernel<<<NTOK, 256, 0, stream>>>(x, projbuf, rms_w, hbuf, hbf);
  transpose_cvt_kernel<<<dim3(IDIM / 32, HDIM / 32, NEXP), 256, 0, stream>>>(
      w1, wT, HDIM, IDIM);
  router_kernel<<<NTOK / 4, 256, 0, stream>>>(hbuf, gate_w, ti, tw);
  scan_kernel<<<1, 64, 0, stream>>>(ti, eidx, counts, slotmap, ebase);
  moe_gemm1_kernel<<<dim3(CAPACITY / 128, IDIM / 128, NEXP), 256, 0, stream>>>(
      hbf, wT, b1, eidx, counts, ebase, h1buf);
  transpose_cvt_kernel<<<dim3(HDIM / 32, IDIM / 32, NEXP), 256, 0, stream>>>(
      w2, wT, IDIM, HDIM);
  moe_gemm2_kernel<<<dim3(CAPACITY / 128, HDIM / 128, NEXP), 256, 0, stream>>>(
      h1buf, wT, b2, counts, ebase, ybuf);
  final_kernel<<<NTOK, 256, 0, stream>>>(hbuf, ybuf, slotmap, tw, ln_w, ln_b,
                                         (float*)d_out);
}

// Round 3
// 639.978 us; speedup vs baseline: 2.1749x; 1.2495x over previous
//
#include <hip/hip_runtime.h>

#define NB 4
#define SQL 1024
#define HDIM 1024
#define NHEAD 16
#define HEADD 64
#define NEXP 8
#define IDIM 2048
#define NTOK (NB*SQL)
#define CAPACITY 2048
#define ATT_SCALE 0.125f

typedef unsigned short u16;
typedef __attribute__((ext_vector_type(8))) short bf16x8;
typedef __attribute__((ext_vector_type(8))) unsigned short u16x8;
typedef __attribute__((ext_vector_type(4))) float f32x4;

__device__ __forceinline__ u16 f2bf(float f) {
  union { float f; unsigned u; } x; x.f = f;
  unsigned r = (x.u + 0x7fffu + ((x.u >> 16) & 1u)) >> 16;
  return (u16)r;
}
__device__ __forceinline__ float bf2f(u16 b) {
  union { unsigned u; float f; } x; x.u = ((unsigned)b) << 16;
  return x.f;
}
__device__ __forceinline__ float wave_sum(float v) {
#pragma unroll
  for (int off = 32; off > 0; off >>= 1) v += __shfl_xor(v, off);
  return v;
}
// async global->LDS, 16B/lane; LDS dest must be wave-uniform base (+lane*16 implicit)
__device__ __forceinline__ void gload_lds16(const u16* g, u16* l) {
  __builtin_amdgcn_global_load_lds(
      (const __attribute__((address_space(1))) void*)g,
      (__attribute__((address_space(3))) void*)l, 16, 0, 0);
}

// ---------------- fp32 -> bf16 row convert (x) ----------------
__global__ __launch_bounds__(256)
void cvt_bf16_kernel(const float* __restrict__ in, u16* __restrict__ out)
{
  size_t i = (size_t)blockIdx.x * 1024 + threadIdx.x * 4;
  float4 v = *(const float4*)&in[i];
  ushort4 o = {f2bf(v.x), f2bf(v.y), f2bf(v.z), f2bf(v.w)};
  *(ushort4*)&out[i] = o;
}

// ---------------- transpose+convert: in fp32 [e][R][C] -> out bf16 [e][C][R] ----------------
__global__ __launch_bounds__(256)
void transpose_cvt_kernel(const float* __restrict__ in, u16* __restrict__ out,
                          int R, int C)
{
  int e = blockIdx.z;
  const float* ine = in + (size_t)e * R * C;
  u16* oute = out + (size_t)e * R * C;
  __shared__ u16 Ts[32 * 34];
  int tx = threadIdx.x & 31, ty = threadIdx.x >> 5;
  int r0 = blockIdx.y * 32, c0 = blockIdx.x * 32;
#pragma unroll
  for (int qq = 0; qq < 4; ++qq) {
    int rr = ty + qq * 8;
    Ts[tx * 34 + rr] = f2bf(ine[(size_t)(r0 + rr) * C + c0 + tx]);
  }
  __syncthreads();
#pragma unroll
  for (int qq = 0; qq < 4; ++qq) {
    int cc = ty + qq * 8;
    oute[(size_t)(c0 + cc) * R + r0 + tx] = Ts[cc * 34 + tx];
  }
}

// ---------------- QKV projection: bf16 MFMA 128x128 tile, K=HDIM ----------------
// global_load_lds staging: linear LDS dest, pre-swizzled per-lane global source.
__global__ __launch_bounds__(256)
void qkv_mfma_kernel(const u16* __restrict__ xbf,
                     const u16* __restrict__ wqT, const u16* __restrict__ wkT,
                     const u16* __restrict__ wvT,
                     const float* __restrict__ bq, const float* __restrict__ bk,
                     const float* __restrict__ bv,
                     u16* __restrict__ q, u16* __restrict__ k, u16* __restrict__ v)
{
  int mode = blockIdx.z;
  const u16* BT   = (mode == 0) ? wqT : (mode == 1) ? wkT : wvT;
  const float* bia = (mode == 0) ? bq : (mode == 1) ? bk : bv;
  u16* dst         = (mode == 0) ? q : (mode == 1) ? k : v;
  int m0 = blockIdx.x * 128, n0 = blockIdx.y * 128;
  __shared__ __align__(16) u16 As[128 * 64];
  __shared__ __align__(16) u16 Bs[128 * 64];
  int tid = threadIdx.x;
  f32x4 acc[4][4];
#pragma unroll
  for (int i = 0; i < 4; ++i)
#pragma unroll
    for (int j = 0; j < 4; ++j) acc[i][j] = (f32x4){0.f, 0.f, 0.f, 0.f};
  int w = tid >> 6, l = tid & 63;
  int lr = l & 15, lq = l >> 4;
  int wm = (w & 1) * 64, wn = (w >> 1) * 64;
  // hoisted staging addresses: slot (r,c) holds global chunk c^(r&7) of row r
  const u16* aptr[4]; const u16* bptr[4]; u16* adst[4]; u16* bdst[4];
#pragma unroll
  for (int p = 0; p < 4; ++p) {
    int flat = p * 256 + tid;
    int r = flat >> 3, c = flat & 7;
    int cs = (c ^ (r & 7)) * 8;
    aptr[p] = xbf + (size_t)(m0 + r) * HDIM + cs;
    bptr[p] = BT + (size_t)(n0 + r) * HDIM + cs;
    adst[p] = &As[(size_t)(p * 256 + w * 64) * 8];
    bdst[p] = &Bs[(size_t)(p * 256 + w * 64) * 8];
  }
  for (int k0 = 0; k0 < HDIM; k0 += 64) {
#pragma unroll
    for (int p = 0; p < 4; ++p) {
      gload_lds16(aptr[p] + k0, adst[p]);
      gload_lds16(bptr[p] + k0, bdst[p]);
    }
    __syncthreads();
#pragma unroll
    for (int s = 0; s < 2; ++s) {
      bf16x8 af[4], bfv[4];
#pragma unroll
      for (int i = 0; i < 4; ++i) {
        int mloc = wm + i * 16 + lr;
        af[i]  = *(const bf16x8*)&As[(mloc * 8 + ((s * 4 + lq) ^ (mloc & 7))) * 8];
        int n = wn + i * 16 + lr;
        bfv[i] = *(const bf16x8*)&Bs[(n * 8 + ((s * 4 + lq) ^ (n & 7))) * 8];
      }
#pragma unroll
      for (int i = 0; i < 4; ++i)
#pragma unroll
        for (int j = 0; j < 4; ++j)
          acc[i][j] = __builtin_amdgcn_mfma_f32_16x16x32_bf16(af[i], bfv[j], acc[i][j], 0, 0, 0);
    }
    __syncthreads();
  }
#pragma unroll
  for (int i = 0; i < 4; ++i)
#pragma unroll
    for (int j = 0; j < 4; ++j) {
      int col = n0 + wn + j * 16 + lr;
      float bb = bia[col];
      int hh = col >> 6, d = col & 63;
#pragma unroll
      for (int r = 0; r < 4; ++r) {
        int tg = m0 + wm + i * 16 + lq * 4 + r;
        int bi = tg >> 10, s = tg & 1023;
        dst[((size_t)(bi * NHEAD + hh) * SQL + s) * HEADD + d] = f2bf(acc[i][j][r] + bb);
      }
    }
}

// ---------------- O-projection: bf16 MFMA, out fp32 [NTOK][HDIM] + bias ----------------
__global__ __launch_bounds__(256)
void proj_mfma_kernel(const u16* __restrict__ aobf, const u16* __restrict__ owT,
                      const float* __restrict__ ob, float* __restrict__ out)
{
  int m0 = blockIdx.x * 128, n0 = blockIdx.y * 128;
  __shared__ __align__(16) u16 As[128 * 64];
  __shared__ __align__(16) u16 Bs[128 * 64];
  int tid = threadIdx.x;
  f32x4 acc[4][4];
#pragma unroll
  for (int i = 0; i < 4; ++i)
#pragma unroll
    for (int j = 0; j < 4; ++j) acc[i][j] = (f32x4){0.f, 0.f, 0.f, 0.f};
  int w = tid >> 6, l = tid & 63;
  int lr = l & 15, lq = l >> 4;
  int wm = (w & 1) * 64, wn = (w >> 1) * 64;
  const u16* aptr[4]; const u16* bptr[4]; u16* adst[4]; u16* bdst[4];
#pragma unroll
  for (int p = 0; p < 4; ++p) {
    int flat = p * 256 + tid;
    int r = flat >> 3, c = flat & 7;
    int cs = (c ^ (r & 7)) * 8;
    aptr[p] = aobf + (size_t)(m0 + r) * HDIM + cs;
    bptr[p] = owT + (size_t)(n0 + r) * HDIM + cs;
    adst[p] = &As[(size_t)(p * 256 + w * 64) * 8];
    bdst[p] = &Bs[(size_t)(p * 256 + w * 64) * 8];
  }
  for (int k0 = 0; k0 < HDIM; k0 += 64) {
#pragma unroll
    for (int p = 0; p < 4; ++p) {
      gload_lds16(aptr[p] + k0, adst[p]);
      gload_lds16(bptr[p] + k0, bdst[p]);
    }
    __syncthreads();
#pragma unroll
    for (int s = 0; s < 2; ++s) {
      bf16x8 af[4], bfv[4];
#pragma unroll
      for (int i = 0; i < 4; ++i) {
        int mloc = wm + i * 16 + lr;
        af[i]  = *(const bf16x8*)&As[(mloc * 8 + ((s * 4 + lq) ^ (mloc & 7))) * 8];
        int n = wn + i * 16 + lr;
        bfv[i] = *(const bf16x8*)&Bs[(n * 8 + ((s * 4 + lq) ^ (n & 7))) * 8];
      }
#pragma unroll
      for (int i = 0; i < 4; ++i)
#pragma unroll
        for (int j = 0; j < 4; ++j)
          acc[i][j] = __builtin_amdgcn_mfma_f32_16x16x32_bf16(af[i], bfv[j], acc[i][j], 0, 0, 0);
    }
    __syncthreads();
  }
#pragma unroll
  for (int i = 0; i < 4; ++i)
#pragma unroll
    for (int j = 0; j < 4; ++j) {
      int col = n0 + wn + j * 16 + lr;
      float bb = ob[col];
#pragma unroll
      for (int r = 0; r < 4; ++r) {
        int tg = m0 + wm + i * 16 + lq * 4 + r;
        out[(size_t)tg * HDIM + col] = acc[i][j][r] + bb;
      }
    }
}

// ---------------- flash attention, bf16 MFMA ----------------
__global__ __launch_bounds__(256)
void attn_mfma_kernel(const u16* __restrict__ q, const u16* __restrict__ k,
                      const u16* __restrict__ v, u16* __restrict__ ao)
{
  __shared__ __align__(16) u16 VT[64 * 72];       // V^T [d][key], stride 72
  __shared__ __align__(16) u16 Pl[4][16 * 72];    // per-wave P [q][key]
  int bid = blockIdx.x;
  int bh = bid & 63;
  int qt = 15 - (bid >> 6);
  int q0 = qt * 64;
  int tid = threadIdx.x;
  int w = tid >> 6, l = tid & 63;
  int lr = l & 15, lq = l >> 4;

  const u16* qp = q + ((size_t)bh * SQL + q0 + w * 16 + lr) * HEADD + lq * 8;
  bf16x8 qf0 = *(const bf16x8*)qp;
  bf16x8 qf1 = *(const bf16x8*)(qp + 32);

  float mrow[4], lrow[4];
  f32x4 Ot[4];
#pragma unroll
  for (int r = 0; r < 4; ++r) { mrow[r] = -1e30f; lrow[r] = 0.f; }
#pragma unroll
  for (int j = 0; j < 4; ++j) Ot[j] = (f32x4){0.f, 0.f, 0.f, 0.f};

  int vkey = 2 * (l & 31);
  int vd0 = w * 16 + (l >> 5) * 8;

  for (int kb = 0; kb <= q0; kb += 64) {
    __syncthreads();
    {
      const u16* vp = v + ((size_t)bh * SQL + kb + vkey) * HEADD + vd0;
      u16x8 a = *(const u16x8*)vp;
      u16x8 b = *(const u16x8*)(vp + HEADD);
#pragma unroll
      for (int e = 0; e < 8; ++e) {
        ushort2 pr = {a[e], b[e]};
        *(ushort2*)&VT[(vd0 + e) * 72 + vkey] = pr;
      }
    }
    f32x4 sacc[4];
#pragma unroll
    for (int j = 0; j < 4; ++j) sacc[j] = (f32x4){0.f, 0.f, 0.f, 0.f};
    const u16* kp = k + ((size_t)bh * SQL + kb + lr) * HEADD + lq * 8;
#pragma unroll
    for (int j = 0; j < 4; ++j) {
      bf16x8 kf0 = *(const bf16x8*)(kp + (size_t)j * 16 * HEADD);
      bf16x8 kf1 = *(const bf16x8*)(kp + (size_t)j * 16 * HEADD + 32);
      sacc[j] = __builtin_amdgcn_mfma_f32_16x16x32_bf16(qf0, kf0, sacc[j], 0, 0, 0);
      sacc[j] = __builtin_amdgcn_mfma_f32_16x16x32_bf16(qf1, kf1, sacc[j], 0, 0, 0);
    }
    bool diag = (kb == q0);
    float pv[4][4];
#pragma unroll
    for (int r = 0; r < 4; ++r) {
      float sv[4];
      float rm = -1e30f;
#pragma unroll
      for (int j = 0; j < 4; ++j) {
        float s0 = sacc[j][r] * ATT_SCALE;
        if (diag && (j * 16 + lr) > (w * 16 + lq * 4 + r)) s0 = -1e30f;
        sv[j] = s0;
        rm = fmaxf(rm, s0);
      }
      rm = fmaxf(rm, __shfl_xor(rm, 1));
      rm = fmaxf(rm, __shfl_xor(rm, 2));
      rm = fmaxf(rm, __shfl_xor(rm, 4));
      rm = fmaxf(rm, __shfl_xor(rm, 8));
      float mnew = fmaxf(mrow[r], rm);
      float alpha = __expf(mrow[r] - mnew);
      mrow[r] = mnew;
      float rl = 0.f;
#pragma unroll
      for (int j = 0; j < 4; ++j) {
        float p = __expf(sv[j] - mnew);
        pv[j][r] = p;
        rl += p;
      }
      rl += __shfl_xor(rl, 1);
      rl += __shfl_xor(rl, 2);
      rl += __shfl_xor(rl, 4);
      rl += __shfl_xor(rl, 8);
      lrow[r] = lrow[r] * alpha + rl;
#pragma unroll
      for (int j2 = 0; j2 < 4; ++j2) Ot[j2][r] *= alpha;
    }
#pragma unroll
    for (int j = 0; j < 4; ++j)
#pragma unroll
      for (int r = 0; r < 4; ++r)
        Pl[w][(lq * 4 + r) * 72 + j * 16 + lr] = f2bf(pv[j][r]);
    __syncthreads();
    const u16* pbase = &Pl[w][lr * 72];
#pragma unroll
    for (int s = 0; s < 2; ++s) {
      bf16x8 pa = *(const bf16x8*)(pbase + s * 32 + lq * 8);
#pragma unroll
      for (int j2 = 0; j2 < 4; ++j2) {
        bf16x8 vb = *(const bf16x8*)&VT[(j2 * 16 + lr) * 72 + s * 32 + lq * 8];
        Ot[j2] = __builtin_amdgcn_mfma_f32_16x16x32_bf16(pa, vb, Ot[j2], 0, 0, 0);
      }
    }
  }
  int b = bh >> 4, hh = bh & 15;
#pragma unroll
  for (int r = 0; r < 4; ++r) {
    float invl = 1.0f / lrow[r];
    int row = q0 + w * 16 + lq * 4 + r;
#pragma unroll
    for (int j2 = 0; j2 < 4; ++j2)
      ao[((size_t)(b * SQL + row)) * HDIM + hh * HEADD + j2 * 16 + lr] =
          f2bf(Ot[j2][r] * invl);
  }
}

// ---------------- residual + RMSNorm (fp32 h out + bf16 copy) ----------------
__global__ __launch_bounds__(256)
void rmsnorm_kernel(const float* __restrict__ x, const float* __restrict__ p,
                    const float* __restrict__ w, float* __restrict__ out,
                    u16* __restrict__ outbf)
{
  int t = blockIdx.x, tid = threadIdx.x;
  float4 xv = ((const float4*)(x + (size_t)t * HDIM))[tid];
  float4 pv = ((const float4*)(p + (size_t)t * HDIM))[tid];
  float4 s = {xv.x + pv.x, xv.y + pv.y, xv.z + pv.z, xv.w + pv.w};
  float ss = s.x * s.x + s.y * s.y + s.z * s.z + s.w * s.w;
  __shared__ float red[4];
  float wsv = wave_sum(ss);
  int wid = tid >> 6, l = tid & 63;
  if (l == 0) red[wid] = wsv;
  __syncthreads();
  float tot = red[0] + red[1] + red[2] + red[3];
  float inv = 1.0f / sqrtf(tot / (float)HDIM + 1e-6f);
  float4 wv = ((const float4*)w)[tid];
  float4 o = {s.x * inv * wv.x, s.y * inv * wv.y, s.z * inv * wv.z, s.w * inv * wv.w};
  ((float4*)(out + (size_t)t * HDIM))[tid] = o;
  ushort4 ob = {f2bf(o.x), f2bf(o.y), f2bf(o.z), f2bf(o.w)};
  ((ushort4*)(outbf + (size_t)t * HDIM))[tid] = ob;
}

// ---------------- router: logits, softmax, top-2, weight norm ----------------
__global__ __launch_bounds__(256)
void router_kernel(const float* __restrict__ h, const float* __restrict__ gw,
                   int* __restrict__ ti, float* __restrict__ tw)
{
  int wid = threadIdx.x >> 6, l = threadIdx.x & 63;
  int t = blockIdx.x * 4 + wid;
  const float* hr = h + (size_t)t * HDIM;
  float hv[16];
#pragma unroll
  for (int j = 0; j < 16; ++j) hv[j] = hr[l + 64 * j];
  float lg[NEXP];
#pragma unroll
  for (int e = 0; e < NEXP; ++e) {
    const float* g = gw + (size_t)e * HDIM;
    float p = 0.f;
#pragma unroll
    for (int j = 0; j < 16; ++j) p += hv[j] * g[l + 64 * j];
    lg[e] = wave_sum(p);
  }
  if (l == 0) {
    int i1 = 0; float m1 = lg[0];
#pragma unroll
    for (int e = 1; e < NEXP; ++e) if (lg[e] > m1) { m1 = lg[e]; i1 = e; }
    int i2 = 0; float m2 = -1e30f;
#pragma unroll
    for (int e = 0; e < NEXP; ++e) if (e != i1 && lg[e] > m2) { m2 = lg[e]; i2 = e; }
    float se = 0.f;
#pragma unroll
    for (int e = 0; e < NEXP; ++e) se += expf(lg[e] - m1);
    float p1 = 1.0f / se;
    float p2 = expf(m2 - m1) / se;
    float denom = p1 + p2 + 1e-20f;
    tw[t * 2]     = p1 / denom * 0.5f;
    tw[t * 2 + 1] = p2 / denom * 0.5f;
    ti[t * 2]     = i1;
    ti[t * 2 + 1] = i2;
  }
}

// ---------------- deterministic capacity scan + packed-row bases ----------------
__global__ void scan_kernel(const int* __restrict__ ti, int* __restrict__ eidx,
                            int* __restrict__ counts, int* __restrict__ slotmap,
                            int* __restrict__ ebase)
{
  int l = threadIdx.x;
  int base[NEXP] = {0, 0, 0, 0, 0, 0, 0, 0};
  unsigned long long below = (l == 0) ? 0ull : ((~0ull) >> (64 - l));
  for (int c2 = 0; c2 < (NTOK * 2) / 64; ++c2) {
    int f = c2 * 64 + l;
    int e = ti[f];
    int mypos = 0;
#pragma unroll
    for (int e0 = 0; e0 < NEXP; ++e0) {
      unsigned long long mm = __ballot(e == e0);
      if (e == e0) mypos = base[e0] + __popcll(mm & below);
      base[e0] += __popcll(mm);
    }
    int slot;
    if (mypos < CAPACITY) {
      slot = e * CAPACITY + mypos;
      eidx[slot] = f >> 1;
    } else slot = -1;
    slotmap[f] = slot;
  }
  int eb[NEXP]; int run = 0;
#pragma unroll
  for (int e = 0; e < NEXP; ++e) {
    eb[e] = run;
    run += (base[e] < CAPACITY) ? base[e] : CAPACITY;
  }
  if (l < NEXP) {
    counts[l] = (base[l] < CAPACITY) ? base[l] : CAPACITY;
    ebase[l] = eb[l];
  }
  for (int c2 = 0; c2 < (NTOK * 2) / 64; ++c2) {
    int f = c2 * 64 + l;
    int vv = slotmap[f];
    if (vv >= 0) slotmap[f] = eb[vv >> 11] + (vv & (CAPACITY - 1));
  }
}

// ---------------- MoE GEMM1: 1D grid, expert = bid&7 (XCD pin), gl_lds staging ------
__global__ __launch_bounds__(256)
void moe_gemm1_kernel(const u16* __restrict__ hbf, const u16* __restrict__ w1T,
                      const float* __restrict__ b1, const int* __restrict__ eidx,
                      const int* __restrict__ counts, const int* __restrict__ ebase,
                      u16* __restrict__ h1)
{
  int bid = blockIdx.x;
  int e = bid & 7;
  int idx = bid >> 3;                 // m fastest within expert
  int m0 = (idx & 15) * 128;
  int n0 = (idx >> 4) * 128;
  int cnt = counts[e];
  if (m0 >= cnt) return;
  int base = ebase[e];
  __shared__ __align__(16) u16 As[128 * 64];
  __shared__ __align__(16) u16 Bs[128 * 64];
  __shared__ int rowtok[128];
  int tid = threadIdx.x;
  if (tid < 128) {
    int r = m0 + tid;
    rowtok[tid] = (r < cnt) ? eidx[e * CAPACITY + r] : 0;   // clamp: dead rows never stored
  }
  __syncthreads();
  const u16* BT = w1T + (size_t)e * IDIM * HDIM;
  f32x4 acc[4][4];
#pragma unroll
  for (int i = 0; i < 4; ++i)
#pragma unroll
    for (int j = 0; j < 4; ++j) acc[i][j] = (f32x4){0.f, 0.f, 0.f, 0.f};
  int w = tid >> 6, l = tid & 63;
  int lr = l & 15, lq = l >> 4;
  int wm = (w & 1) * 64, wn = (w >> 1) * 64;
  const u16* aptr[4]; const u16* bptr[4]; u16* adst[4]; u16* bdst[4];
#pragma unroll
  for (int p = 0; p < 4; ++p) {
    int flat = p * 256 + tid;
    int r = flat >> 3, c = flat & 7;
    int cs = (c ^ (r & 7)) * 8;
    aptr[p] = hbf + (size_t)rowtok[r] * HDIM + cs;
    bptr[p] = BT + (size_t)(n0 + r) * HDIM + cs;
    adst[p] = &As[(size_t)(p * 256 + w * 64) * 8];
    bdst[p] = &Bs[(size_t)(p * 256 + w * 64) * 8];
  }
  for (int k0 = 0; k0 < HDIM; k0 += 64) {
#pragma unroll
    for (int p = 0; p < 4; ++p) {
      gload_lds16(aptr[p] + k0, adst[p]);
      gload_lds16(bptr[p] + k0, bdst[p]);
    }
    __syncthreads();
#pragma unroll
    for (int s = 0; s < 2; ++s) {
      bf16x8 af[4], bfv[4];
#pragma unroll
      for (int i = 0; i < 4; ++i) {
        int mloc = wm + i * 16 + lr;
        af[i]  = *(const bf16x8*)&As[(mloc * 8 + ((s * 4 + lq) ^ (mloc & 7))) * 8];
        int n = wn + i * 16 + lr;
        bfv[i] = *(const bf16x8*)&Bs[(n * 8 + ((s * 4 + lq) ^ (n & 7))) * 8];
      }
#pragma unroll
      for (int i = 0; i < 4; ++i)
#pragma unroll
        for (int j = 0; j < 4; ++j)
          acc[i][j] = __builtin_amdgcn_mfma_f32_16x16x32_bf16(af[i], bfv[j], acc[i][j], 0, 0, 0);
    }
    __syncthreads();
  }
#pragma unroll
  for (int i = 0; i < 4; ++i)
#pragma unroll
    for (int j = 0; j < 4; ++j) {
      int col = n0 + wn + j * 16 + lr;
      float bb = b1[(size_t)e * IDIM + col];
#pragma unroll
      for (int r = 0; r < 4; ++r) {
        int rowl = m0 + wm + i * 16 + lq * 4 + r;
        if (rowl < cnt) {
          float y = acc[i][j][r] + bb;
          float g = 0.5f * y * (1.0f + erff(y * 0.70710678118654752f));
          h1[(size_t)(base + rowl) * IDIM + col] = f2bf(g);
        }
      }
    }
}

// ---------------- MoE GEMM2: 1D grid, expert = bid&7 (XCD pin), gl_lds staging ------
__global__ __launch_bounds__(256)
void moe_gemm2_kernel(const u16* __restrict__ h1, const u16* __restrict__ w2T,
                      const float* __restrict__ b2, const int* __restrict__ counts,
                      const int* __restrict__ ebase, u16* __restrict__ ybuf)
{
  int bid = blockIdx.x;
  int e = bid & 7;
  int idx = bid >> 3;                 // m fastest within expert
  int m0 = (idx & 15) * 128;
  int n0 = (idx >> 4) * 128;
  int cnt = counts[e];
  if (m0 >= cnt) return;
  int base = ebase[e];
  __shared__ __align__(16) u16 As[128 * 64];
  __shared__ __align__(16) u16 Bs[128 * 64];
  int tid = threadIdx.x;
  const u16* BT = w2T + (size_t)e * HDIM * IDIM;
  f32x4 acc[4][4];
#pragma unroll
  for (int i = 0; i < 4; ++i)
#pragma unroll
    for (int j = 0; j < 4; ++j) acc[i][j] = (f32x4){0.f, 0.f, 0.f, 0.f};
  int w = tid >> 6, l = tid & 63;
  int lr = l & 15, lq = l >> 4;
  int wm = (w & 1) * 64, wn = (w >> 1) * 64;
  const u16* aptr[4]; const u16* bptr[4]; u16* adst[4]; u16* bdst[4];
#pragma unroll
  for (int p = 0; p < 4; ++p) {
    int flat = p * 256 + tid;
    int r = flat >> 3, c = flat & 7;
    int cs = (c ^ (r & 7)) * 8;
    int rowg = m0 + r;
    if (rowg >= cnt) rowg = cnt - 1;  // clamp: dead rows never stored
    aptr[p] = h1 + (size_t)(base + rowg) * IDIM + cs;
    bptr[p] = BT + (size_t)(n0 + r) * IDIM + cs;
    adst[p] = &As[(size_t)(p * 256 + w * 64) * 8];
    bdst[p] = &Bs[(size_t)(p * 256 + w * 64) * 8];
  }
  for (int k0 = 0; k0 < IDIM; k0 += 64) {
#pragma unroll
    for (int p = 0; p < 4; ++p) {
      gload_lds16(aptr[p] + k0, adst[p]);
      gload_lds16(bptr[p] + k0, bdst[p]);
    }
    __syncthreads();
#pragma unroll
    for (int s = 0; s < 2; ++s) {
      bf16x8 af[4], bfv[4];
#pragma unroll
      for (int i = 0; i < 4; ++i) {
        int mloc = wm + i * 16 + lr;
        af[i]  = *(const bf16x8*)&As[(mloc * 8 + ((s * 4 + lq) ^ (mloc & 7))) * 8];
        int n = wn + i * 16 + lr;
        bfv[i] = *(const bf16x8*)&Bs[(n * 8 + ((s * 4 + lq) ^ (n & 7))) * 8];
      }
#pragma unroll
      for (int i = 0; i < 4; ++i)
#pragma unroll
        for (int j = 0; j < 4; ++j)
          acc[i][j] = __builtin_amdgcn_mfma_f32_16x16x32_bf16(af[i], bfv[j], acc[i][j], 0, 0, 0);
    }
    __syncthreads();
  }
#pragma unroll
  for (int i = 0; i < 4; ++i)
#pragma unroll
    for (int j = 0; j < 4; ++j) {
      int col = n0 + wn + j * 16 + lr;
      float bb = b2[(size_t)e * HDIM + col];
#pragma unroll
      for (int r = 0; r < 4; ++r) {
        int rowl = m0 + wm + i * 16 + lq * 4 + r;
        if (rowl < cnt)
          ybuf[(size_t)(base + rowl) * HDIM + col] = f2bf(acc[i][j][r] + bb);
      }
    }
}

// ---------------- final: h + sum_k tw_k * y[row_k] -> LayerNorm -> fp32 out ----------------
__global__ __launch_bounds__(256)
void final_kernel(const float* __restrict__ h, const u16* __restrict__ ybuf,
                  const int* __restrict__ slotmap, const float* __restrict__ tw,
                  const float* __restrict__ lnw, const float* __restrict__ lnb,
                  float* __restrict__ out)
{
  int t = blockIdx.x, tid = threadIdx.x;
  int s0 = slotmap[t * 2], s1 = slotmap[t * 2 + 1];
  float w0 = tw[t * 2], w1v = tw[t * 2 + 1];
  float4 hv = ((const float4*)(h + (size_t)t * HDIM))[tid];
  float vals[4] = {hv.x, hv.y, hv.z, hv.w};
  if (s0 >= 0) {
    const u16* yr = ybuf + (size_t)s0 * HDIM + tid * 4;
#pragma unroll
    for (int j = 0; j < 4; ++j) vals[j] += w0 * bf2f(yr[j]);
  }
  if (s1 >= 0) {
    const u16* yr = ybuf + (size_t)s1 * HDIM + tid * 4;
#pragma unroll
    for (int j = 0; j < 4; ++j) vals[j] += w1v * bf2f(yr[j]);
  }
  float s = vals[0] + vals[1] + vals[2] + vals[3];
  float q2 = vals[0] * vals[0] + vals[1] * vals[1] + vals[2] * vals[2] + vals[3] * vals[3];
  __shared__ float reds[4], redq[4];
  float wsv = wave_sum(s), wqv = wave_sum(q2);
  int wid = tid >> 6, l = tid & 63;
  if (l == 0) { reds[wid] = wsv; redq[wid] = wqv; }
  __syncthreads();
  float tot = reds[0] + reds[1] + reds[2] + reds[3];
  float totq = redq[0] + redq[1] + redq[2] + redq[3];
  float mu = tot / 1024.0f;
  float var = totq / 1024.0f - mu * mu;
  float inv = 1.0f / sqrtf(var + 1e-6f);
#pragma unroll
  for (int j = 0; j < 4; ++j) {
    int c = tid * 4 + j;
    out[(size_t)t * HDIM + c] = (vals[j] - mu) * inv * lnw[c] + lnb[c];
  }
}

extern "C" void kernel_launch(void* const* d_in, const int* in_sizes, int n_in,
                              void* d_out, int out_size, void* d_ws, size_t ws_size,
                              hipStream_t stream)
{
  const float* x      = (const float*)d_in[0];
  const float* qw     = (const float*)d_in[2];
  const float* qb     = (const float*)d_in[3];
  const float* kw     = (const float*)d_in[4];
  const float* kb     = (const float*)d_in[5];
  const float* vw     = (const float*)d_in[6];
  const float* vb     = (const float*)d_in[7];
  const float* ow     = (const float*)d_in[8];
  const float* ob     = (const float*)d_in[9];
  const float* rms_w  = (const float*)d_in[10];
  const float* gate_w = (const float*)d_in[11];
  const float* w1     = (const float*)d_in[12];
  const float* b1     = (const float*)d_in[13];
  const float* w2     = (const float*)d_in[14];
  const float* b2     = (const float*)d_in[15];
  const float* ln_w   = (const float*)d_in[16];
  const float* ln_b   = (const float*)d_in[17];

  char* ws = (char*)d_ws;
  const size_t MB = 1024ull * 1024ull;
  u16*   qbf    = (u16*)(ws + 0 * MB);     // 8MB bf16 q [bh][s][d]
  u16*   kbf    = (u16*)(ws + 8 * MB);     // 8MB
  u16*   vbf    = (u16*)(ws + 16 * MB);    // 8MB
  u16*   aobf   = (u16*)(ws + 24 * MB);    // 8MB bf16 attn-out [tok][H]
  u16*   xbf    = (u16*)(ws + 32 * MB);    // 8MB bf16 x
  u16*   wqT    = (u16*)(ws + 40 * MB);    // 2MB
  u16*   wkT    = (u16*)(ws + 42 * MB);    // 2MB
  u16*   wvT    = (u16*)(ws + 44 * MB);    // 2MB
  u16*   owT    = (u16*)(ws + 46 * MB);    // 2MB
  float* projbuf= (float*)(ws + 48 * MB);  // 16MB fp32 attn-proj out
  float* hbuf   = (float*)(ws + 64 * MB);  // 16MB fp32 h
  u16*   hbf    = (u16*)(ws + 80 * MB);    // 8MB bf16 h
  u16*   wT     = (u16*)(ws + 0 * MB);     // MoE weight^T staging, 32MB (q/k/v/ao dead)
  u16*   ybuf   = (u16*)(ws + 32 * MB);    // 16MB (xbf + w*T dead)
  u16*   h1buf  = (u16*)(ws + 88 * MB);    // 32MB
  char*  sm     = ws + 120 * MB;
  int*   ti      = (int*)(sm);
  float* tw      = (float*)(sm + 32 * 1024);
  int*   eidx    = (int*)(sm + 64 * 1024);
  int*   slotmap = (int*)(sm + 128 * 1024);
  int*   counts  = (int*)(sm + 160 * 1024);
  int*   ebase   = (int*)(sm + 164 * 1024);

  cvt_bf16_kernel<<<NTOK, 256, 0, stream>>>(x, xbf);
  transpose_cvt_kernel<<<dim3(32, 32, 1), 256, 0, stream>>>(qw, wqT, HDIM, HDIM);
  transpose_cvt_kernel<<<dim3(32, 32, 1), 256, 0, stream>>>(kw, wkT, HDIM, HDIM);
  transpose_cvt_kernel<<<dim3(32, 32, 1), 256, 0, stream>>>(vw, wvT, HDIM, HDIM);
  transpose_cvt_kernel<<<dim3(32, 32, 1), 256, 0, stream>>>(ow, owT, HDIM, HDIM);
  qkv_mfma_kernel<<<dim3(NTOK / 128, HDIM / 128, 3), 256, 0, stream>>>(
      xbf, wqT, wkT, wvT, qb, kb, vb, qbf, kbf, vbf);
  attn_mfma_kernel<<<NB * NHEAD * (SQL / 64), 256, 0, stream>>>(qbf, kbf, vbf, aobf);
  proj_mfma_kernel<<<dim3(NTOK / 128, HDIM / 128), 256, 0, stream>>>(
      aobf, owT, ob, projbuf);
  rmsnorm_kernel<<<NTOK, 256, 0, stream>>>(x, projbuf, rms_w, hbuf, hbf);
  transpose_cvt_kernel<<<dim3(IDIM / 32, HDIM / 32, NEXP), 256, 0, stream>>>(
      w1, wT, HDIM, IDIM);
  router_kernel<<<NTOK / 4, 256, 0, stream>>>(hbuf, gate_w, ti, tw);
  scan_kernel<<<1, 64, 0, stream>>>(ti, eidx, counts, slotmap, ebase);
  moe_gemm1_kernel<<<dim3(NEXP * (CAPACITY / 128) * (IDIM / 128)), 256, 0, stream>>>(
      hbf, wT, b1, eidx, counts, ebase, h1buf);
  transpose_cvt_kernel<<<dim3(HDIM / 32, IDIM / 32, NEXP), 256, 0, stream>>>(
      w2, wT, IDIM, HDIM);
  moe_gemm2_kernel<<<dim3(NEXP * (CAPACITY / 128) * (HDIM / 128)), 256, 0, stream>>>(
      h1buf, wT, b2, counts, ebase, ybuf);
  final_kernel<<<NTOK, 256, 0, stream>>>(hbuf, ybuf, slotmap, tw, ln_w, ln_b,
                                         (float*)d_out);
}

// Round 4
// 534.061 us; speedup vs baseline: 2.6062x; 1.1983x over previous
//
#include <hip/hip_runtime.h>

#define NB 4
#define SQL 1024
#define HDIM 1024
#define NHEAD 16
#define HEADD 64
#define NEXP 8
#define IDIM 2048
#define NTOK (NB*SQL)
#define CAPACITY 2048
#define ATT_SCALE 0.125f

typedef unsigned short u16;
typedef __attribute__((ext_vector_type(8))) short bf16x8;
typedef __attribute__((ext_vector_type(8))) unsigned short u16x8;
typedef __attribute__((ext_vector_type(4))) float f32x4;

__device__ __forceinline__ u16 f2bf(float f) {
  union { float f; unsigned u; } x; x.f = f;
  unsigned r = (x.u + 0x7fffu + ((x.u >> 16) & 1u)) >> 16;
  return (u16)r;
}
__device__ __forceinline__ float bf2f(u16 b) {
  union { unsigned u; float f; } x; x.u = ((unsigned)b) << 16;
  return x.f;
}
__device__ __forceinline__ float wave_sum(float v) {
#pragma unroll
  for (int off = 32; off > 0; off >>= 1) v += __shfl_xor(v, off);
  return v;
}
// async global->LDS, 16B/lane; LDS dest must be wave-uniform base (+lane*16 implicit)
__device__ __forceinline__ void gload_lds16(const u16* g, u16* l) {
  __builtin_amdgcn_global_load_lds(
      (const __attribute__((address_space(1))) void*)g,
      (__attribute__((address_space(3))) void*)l, 16, 0, 0);
}

// ---------------- fp32 -> bf16 row convert (x) ----------------
__global__ __launch_bounds__(256)
void cvt_bf16_kernel(const float* __restrict__ in, u16* __restrict__ out)
{
  size_t i = (size_t)blockIdx.x * 1024 + threadIdx.x * 4;
  float4 v = *(const float4*)&in[i];
  ushort4 o = {f2bf(v.x), f2bf(v.y), f2bf(v.z), f2bf(v.w)};
  *(ushort4*)&out[i] = o;
}

// ---------------- transpose+convert: in fp32 [e][R][C] -> out bf16 [e][C][R] ----------------
__global__ __launch_bounds__(256)
void transpose_cvt_kernel(const float* __restrict__ in, u16* __restrict__ out,
                          int R, int C)
{
  int e = blockIdx.z;
  const float* ine = in + (size_t)e * R * C;
  u16* oute = out + (size_t)e * R * C;
  __shared__ u16 Ts[32 * 34];
  int tx = threadIdx.x & 31, ty = threadIdx.x >> 5;
  int r0 = blockIdx.y * 32, c0 = blockIdx.x * 32;
#pragma unroll
  for (int qq = 0; qq < 4; ++qq) {
    int rr = ty + qq * 8;
    Ts[tx * 34 + rr] = f2bf(ine[(size_t)(r0 + rr) * C + c0 + tx]);
  }
  __syncthreads();
#pragma unroll
  for (int qq = 0; qq < 4; ++qq) {
    int cc = ty + qq * 8;
    oute[(size_t)(c0 + cc) * R + r0 + tx] = Ts[cc * 34 + tx];
  }
}

// ---------------- QKV projection: bf16 MFMA 128x128 tile, K=HDIM ----------------
__global__ __launch_bounds__(256)
void qkv_mfma_kernel(const u16* __restrict__ xbf,
                     const u16* __restrict__ wqT, const u16* __restrict__ wkT,
                     const u16* __restrict__ wvT,
                     const float* __restrict__ bq, const float* __restrict__ bk,
                     const float* __restrict__ bv,
                     u16* __restrict__ q, u16* __restrict__ k, u16* __restrict__ v)
{
  int mode = blockIdx.z;
  const u16* BT   = (mode == 0) ? wqT : (mode == 1) ? wkT : wvT;
  const float* bia = (mode == 0) ? bq : (mode == 1) ? bk : bv;
  u16* dst         = (mode == 0) ? q : (mode == 1) ? k : v;
  int m0 = blockIdx.x * 128, n0 = blockIdx.y * 128;
  __shared__ __align__(16) u16 As[128 * 64];
  __shared__ __align__(16) u16 Bs[128 * 64];
  int tid = threadIdx.x;
  f32x4 acc[4][4];
#pragma unroll
  for (int i = 0; i < 4; ++i)
#pragma unroll
    for (int j = 0; j < 4; ++j) acc[i][j] = (f32x4){0.f, 0.f, 0.f, 0.f};
  int w = tid >> 6, l = tid & 63;
  int lr = l & 15, lq = l >> 4;
  int wm = (w & 1) * 64, wn = (w >> 1) * 64;
  const u16* aptr[4]; const u16* bptr[4]; u16* adst[4]; u16* bdst[4];
#pragma unroll
  for (int p = 0; p < 4; ++p) {
    int flat = p * 256 + tid;
    int r = flat >> 3, c = flat & 7;
    int cs = (c ^ (r & 7)) * 8;
    aptr[p] = xbf + (size_t)(m0 + r) * HDIM + cs;
    bptr[p] = BT + (size_t)(n0 + r) * HDIM + cs;
    adst[p] = &As[(size_t)(p * 256 + w * 64) * 8];
    bdst[p] = &Bs[(size_t)(p * 256 + w * 64) * 8];
  }
  for (int k0 = 0; k0 < HDIM; k0 += 64) {
#pragma unroll
    for (int p = 0; p < 4; ++p) {
      gload_lds16(aptr[p] + k0, adst[p]);
      gload_lds16(bptr[p] + k0, bdst[p]);
    }
    __syncthreads();
#pragma unroll
    for (int s = 0; s < 2; ++s) {
      bf16x8 af[4], bfv[4];
#pragma unroll
      for (int i = 0; i < 4; ++i) {
        int mloc = wm + i * 16 + lr;
        af[i]  = *(const bf16x8*)&As[(mloc * 8 + ((s * 4 + lq) ^ (mloc & 7))) * 8];
        int n = wn + i * 16 + lr;
        bfv[i] = *(const bf16x8*)&Bs[(n * 8 + ((s * 4 + lq) ^ (n & 7))) * 8];
      }
#pragma unroll
      for (int i = 0; i < 4; ++i)
#pragma unroll
        for (int j = 0; j < 4; ++j)
          acc[i][j] = __builtin_amdgcn_mfma_f32_16x16x32_bf16(af[i], bfv[j], acc[i][j], 0, 0, 0);
    }
    __syncthreads();
  }
#pragma unroll
  for (int i = 0; i < 4; ++i)
#pragma unroll
    for (int j = 0; j < 4; ++j) {
      int col = n0 + wn + j * 16 + lr;
      float bb = bia[col];
      int hh = col >> 6, d = col & 63;
#pragma unroll
      for (int r = 0; r < 4; ++r) {
        int tg = m0 + wm + i * 16 + lq * 4 + r;
        int bi = tg >> 10, s = tg & 1023;
        dst[((size_t)(bi * NHEAD + hh) * SQL + s) * HEADD + d] = f2bf(acc[i][j][r] + bb);
      }
    }
}

// ---------------- O-projection: bf16 MFMA, out fp32 [NTOK][HDIM] + bias ----------------
__global__ __launch_bounds__(256)
void proj_mfma_kernel(const u16* __restrict__ aobf, const u16* __restrict__ owT,
                      const float* __restrict__ ob, float* __restrict__ out)
{
  int m0 = blockIdx.x * 128, n0 = blockIdx.y * 128;
  __shared__ __align__(16) u16 As[128 * 64];
  __shared__ __align__(16) u16 Bs[128 * 64];
  int tid = threadIdx.x;
  f32x4 acc[4][4];
#pragma unroll
  for (int i = 0; i < 4; ++i)
#pragma unroll
    for (int j = 0; j < 4; ++j) acc[i][j] = (f32x4){0.f, 0.f, 0.f, 0.f};
  int w = tid >> 6, l = tid & 63;
  int lr = l & 15, lq = l >> 4;
  int wm = (w & 1) * 64, wn = (w >> 1) * 64;
  const u16* aptr[4]; const u16* bptr[4]; u16* adst[4]; u16* bdst[4];
#pragma unroll
  for (int p = 0; p < 4; ++p) {
    int flat = p * 256 + tid;
    int r = flat >> 3, c = flat & 7;
    int cs = (c ^ (r & 7)) * 8;
    aptr[p] = aobf + (size_t)(m0 + r) * HDIM + cs;
    bptr[p] = owT + (size_t)(n0 + r) * HDIM + cs;
    adst[p] = &As[(size_t)(p * 256 + w * 64) * 8];
    bdst[p] = &Bs[(size_t)(p * 256 + w * 64) * 8];
  }
  for (int k0 = 0; k0 < HDIM; k0 += 64) {
#pragma unroll
    for (int p = 0; p < 4; ++p) {
      gload_lds16(aptr[p] + k0, adst[p]);
      gload_lds16(bptr[p] + k0, bdst[p]);
    }
    __syncthreads();
#pragma unroll
    for (int s = 0; s < 2; ++s) {
      bf16x8 af[4], bfv[4];
#pragma unroll
      for (int i = 0; i < 4; ++i) {
        int mloc = wm + i * 16 + lr;
        af[i]  = *(const bf16x8*)&As[(mloc * 8 + ((s * 4 + lq) ^ (mloc & 7))) * 8];
        int n = wn + i * 16 + lr;
        bfv[i] = *(const bf16x8*)&Bs[(n * 8 + ((s * 4 + lq) ^ (n & 7))) * 8];
      }
#pragma unroll
      for (int i = 0; i < 4; ++i)
#pragma unroll
        for (int j = 0; j < 4; ++j)
          acc[i][j] = __builtin_amdgcn_mfma_f32_16x16x32_bf16(af[i], bfv[j], acc[i][j], 0, 0, 0);
    }
    __syncthreads();
  }
#pragma unroll
  for (int i = 0; i < 4; ++i)
#pragma unroll
    for (int j = 0; j < 4; ++j) {
      int col = n0 + wn + j * 16 + lr;
      float bb = ob[col];
#pragma unroll
      for (int r = 0; r < 4; ++r) {
        int tg = m0 + wm + i * 16 + lq * 4 + r;
        out[(size_t)tg * HDIM + col] = acc[i][j][r] + bb;
      }
    }
}

// ---------------- flash attention, bf16 MFMA ----------------
__global__ __launch_bounds__(256)
void attn_mfma_kernel(const u16* __restrict__ q, const u16* __restrict__ k,
                      const u16* __restrict__ v, u16* __restrict__ ao)
{
  __shared__ __align__(16) u16 VT[64 * 72];       // V^T [d][key], stride 72
  __shared__ __align__(16) u16 Pl[4][16 * 72];    // per-wave P [q][key]
  int bid = blockIdx.x;
  int bh = bid & 63;
  int qt = 15 - (bid >> 6);
  int q0 = qt * 64;
  int tid = threadIdx.x;
  int w = tid >> 6, l = tid & 63;
  int lr = l & 15, lq = l >> 4;

  const u16* qp = q + ((size_t)bh * SQL + q0 + w * 16 + lr) * HEADD + lq * 8;
  bf16x8 qf0 = *(const bf16x8*)qp;
  bf16x8 qf1 = *(const bf16x8*)(qp + 32);

  float mrow[4], lrow[4];
  f32x4 Ot[4];
#pragma unroll
  for (int r = 0; r < 4; ++r) { mrow[r] = -1e30f; lrow[r] = 0.f; }
#pragma unroll
  for (int j = 0; j < 4; ++j) Ot[j] = (f32x4){0.f, 0.f, 0.f, 0.f};

  int vkey = 2 * (l & 31);
  int vd0 = w * 16 + (l >> 5) * 8;

  for (int kb = 0; kb <= q0; kb += 64) {
    __syncthreads();
    {
      const u16* vp = v + ((size_t)bh * SQL + kb + vkey) * HEADD + vd0;
      u16x8 a = *(const u16x8*)vp;
      u16x8 b = *(const u16x8*)(vp + HEADD);
#pragma unroll
      for (int e = 0; e < 8; ++e) {
        ushort2 pr = {a[e], b[e]};
        *(ushort2*)&VT[(vd0 + e) * 72 + vkey] = pr;
      }
    }
    f32x4 sacc[4];
#pragma unroll
    for (int j = 0; j < 4; ++j) sacc[j] = (f32x4){0.f, 0.f, 0.f, 0.f};
    const u16* kp = k + ((size_t)bh * SQL + kb + lr) * HEADD + lq * 8;
#pragma unroll
    for (int j = 0; j < 4; ++j) {
      bf16x8 kf0 = *(const bf16x8*)(kp + (size_t)j * 16 * HEADD);
      bf16x8 kf1 = *(const bf16x8*)(kp + (size_t)j * 16 * HEADD + 32);
      sacc[j] = __builtin_amdgcn_mfma_f32_16x16x32_bf16(qf0, kf0, sacc[j], 0, 0, 0);
      sacc[j] = __builtin_amdgcn_mfma_f32_16x16x32_bf16(qf1, kf1, sacc[j], 0, 0, 0);
    }
    bool diag = (kb == q0);
    float pv[4][4];
#pragma unroll
    for (int r = 0; r < 4; ++r) {
      float sv[4];
      float rm = -1e30f;
#pragma unroll
      for (int j = 0; j < 4; ++j) {
        float s0 = sacc[j][r] * ATT_SCALE;
        if (diag && (j * 16 + lr) > (w * 16 + lq * 4 + r)) s0 = -1e30f;
        sv[j] = s0;
        rm = fmaxf(rm, s0);
      }
      rm = fmaxf(rm, __shfl_xor(rm, 1));
      rm = fmaxf(rm, __shfl_xor(rm, 2));
      rm = fmaxf(rm, __shfl_xor(rm, 4));
      rm = fmaxf(rm, __shfl_xor(rm, 8));
      float mnew = fmaxf(mrow[r], rm);
      float alpha = __expf(mrow[r] - mnew);
      mrow[r] = mnew;
      float rl = 0.f;
#pragma unroll
      for (int j = 0; j < 4; ++j) {
        float p = __expf(sv[j] - mnew);
        pv[j][r] = p;
        rl += p;
      }
      rl += __shfl_xor(rl, 1);
      rl += __shfl_xor(rl, 2);
      rl += __shfl_xor(rl, 4);
      rl += __shfl_xor(rl, 8);
      lrow[r] = lrow[r] * alpha + rl;
#pragma unroll
      for (int j2 = 0; j2 < 4; ++j2) Ot[j2][r] *= alpha;
    }
#pragma unroll
    for (int j = 0; j < 4; ++j)
#pragma unroll
      for (int r = 0; r < 4; ++r)
        Pl[w][(lq * 4 + r) * 72 + j * 16 + lr] = f2bf(pv[j][r]);
    __syncthreads();
    const u16* pbase = &Pl[w][lr * 72];
#pragma unroll
    for (int s = 0; s < 2; ++s) {
      bf16x8 pa = *(const bf16x8*)(pbase + s * 32 + lq * 8);
#pragma unroll
      for (int j2 = 0; j2 < 4; ++j2) {
        bf16x8 vb = *(const bf16x8*)&VT[(j2 * 16 + lr) * 72 + s * 32 + lq * 8];
        Ot[j2] = __builtin_amdgcn_mfma_f32_16x16x32_bf16(pa, vb, Ot[j2], 0, 0, 0);
      }
    }
  }
  int b = bh >> 4, hh = bh & 15;
#pragma unroll
  for (int r = 0; r < 4; ++r) {
    float invl = 1.0f / lrow[r];
    int row = q0 + w * 16 + lq * 4 + r;
#pragma unroll
    for (int j2 = 0; j2 < 4; ++j2)
      ao[((size_t)(b * SQL + row)) * HDIM + hh * HEADD + j2 * 16 + lr] =
          f2bf(Ot[j2][r] * invl);
  }
}

// ---------------- residual + RMSNorm (fp32 h out + bf16 copy) ----------------
__global__ __launch_bounds__(256)
void rmsnorm_kernel(const float* __restrict__ x, const float* __restrict__ p,
                    const float* __restrict__ w, float* __restrict__ out,
                    u16* __restrict__ outbf)
{
  int t = blockIdx.x, tid = threadIdx.x;
  float4 xv = ((const float4*)(x + (size_t)t * HDIM))[tid];
  float4 pv = ((const float4*)(p + (size_t)t * HDIM))[tid];
  float4 s = {xv.x + pv.x, xv.y + pv.y, xv.z + pv.z, xv.w + pv.w};
  float ss = s.x * s.x + s.y * s.y + s.z * s.z + s.w * s.w;
  __shared__ float red[4];
  float wsv = wave_sum(ss);
  int wid = tid >> 6, l = tid & 63;
  if (l == 0) red[wid] = wsv;
  __syncthreads();
  float tot = red[0] + red[1] + red[2] + red[3];
  float inv = 1.0f / sqrtf(tot / (float)HDIM + 1e-6f);
  float4 wv = ((const float4*)w)[tid];
  float4 o = {s.x * inv * wv.x, s.y * inv * wv.y, s.z * inv * wv.z, s.w * inv * wv.w};
  ((float4*)(out + (size_t)t * HDIM))[tid] = o;
  ushort4 ob = {f2bf(o.x), f2bf(o.y), f2bf(o.z), f2bf(o.w)};
  ((ushort4*)(outbf + (size_t)t * HDIM))[tid] = ob;
}

// ---------------- router: logits, softmax, top-2, weight norm ----------------
__global__ __launch_bounds__(256)
void router_kernel(const float* __restrict__ h, const float* __restrict__ gw,
                   int* __restrict__ ti, float* __restrict__ tw)
{
  int wid = threadIdx.x >> 6, l = threadIdx.x & 63;
  int t = blockIdx.x * 4 + wid;
  const float* hr = h + (size_t)t * HDIM;
  float hv[16];
#pragma unroll
  for (int j = 0; j < 16; ++j) hv[j] = hr[l + 64 * j];
  float lg[NEXP];
#pragma unroll
  for (int e = 0; e < NEXP; ++e) {
    const float* g = gw + (size_t)e * HDIM;
    float p = 0.f;
#pragma unroll
    for (int j = 0; j < 16; ++j) p += hv[j] * g[l + 64 * j];
    lg[e] = wave_sum(p);
  }
  if (l == 0) {
    int i1 = 0; float m1 = lg[0];
#pragma unroll
    for (int e = 1; e < NEXP; ++e) if (lg[e] > m1) { m1 = lg[e]; i1 = e; }
    int i2 = 0; float m2 = -1e30f;
#pragma unroll
    for (int e = 0; e < NEXP; ++e) if (e != i1 && lg[e] > m2) { m2 = lg[e]; i2 = e; }
    float se = 0.f;
#pragma unroll
    for (int e = 0; e < NEXP; ++e) se += expf(lg[e] - m1);
    float p1 = 1.0f / se;
    float p2 = expf(m2 - m1) / se;
    float denom = p1 + p2 + 1e-20f;
    tw[t * 2]     = p1 / denom * 0.5f;
    tw[t * 2 + 1] = p2 / denom * 0.5f;
    ti[t * 2]     = i1;
    ti[t * 2 + 1] = i2;
  }
}

// ---------------- parallel deterministic capacity scan (16 waves, 3 phases) ----------------
__global__ __launch_bounds__(1024)
void scan_kernel(const int* __restrict__ ti, int* __restrict__ eidx,
                 int* __restrict__ counts, int* __restrict__ slotmap,
                 int* __restrict__ ebase)
{
  __shared__ int wc[16][NEXP];     // per-wave per-expert chunk counts
  __shared__ int wbase[16][NEXP];  // exclusive prefix across waves
  __shared__ int tot[NEXP];
  __shared__ int eb[NEXP];
  int tid = threadIdx.x;
  int w = tid >> 6, l = tid & 63;
  unsigned long long below = (l == 0) ? 0ull : ((~0ull) >> (64 - l));
  const int CH = (NTOK * 2) / 16;                // 512 entries per wave
  const int RND = CH / 64;                       // 8 rounds
  int ev[RND];
  int myc[NEXP];
#pragma unroll
  for (int e = 0; e < NEXP; ++e) myc[e] = 0;
  // phase 1: per-wave per-expert counts (cache ti in registers)
#pragma unroll
  for (int c2 = 0; c2 < RND; ++c2) {
    int f = w * CH + c2 * 64 + l;
    int e = ti[f];
    ev[c2] = e;
#pragma unroll
    for (int e0 = 0; e0 < NEXP; ++e0)
      myc[e0] += __popcll(__ballot(e == e0));
  }
  if (l == 0) {
#pragma unroll
    for (int e = 0; e < NEXP; ++e) wc[w][e] = myc[e];
  }
  __syncthreads();
  // phase 2: cross-wave exclusive scan per expert; totals; packed bases
  if (tid < NEXP) {
    int run = 0;
#pragma unroll
    for (int ww = 0; ww < 16; ++ww) { wbase[ww][tid] = run; run += wc[ww][tid]; }
    tot[tid] = run;
    counts[tid] = (run < CAPACITY) ? run : CAPACITY;
  }
  __syncthreads();
  if (tid == 0) {
    int run = 0;
#pragma unroll
    for (int e = 0; e < NEXP; ++e) {
      eb[e] = run;
      ebase[e] = run;
      int c = tot[e];
      run += (c < CAPACITY) ? c : CAPACITY;
    }
  }
  __syncthreads();
  // phase 3: exact positions from scanned bases; write eidx + packed slotmap
  int base[NEXP];
#pragma unroll
  for (int e = 0; e < NEXP; ++e) base[e] = wbase[w][e];
#pragma unroll
  for (int c2 = 0; c2 < RND; ++c2) {
    int f = w * CH + c2 * 64 + l;
    int e = ev[c2];
    int mypos = 0;
#pragma unroll
    for (int e0 = 0; e0 < NEXP; ++e0) {
      unsigned long long mm = __ballot(e == e0);
      if (e == e0) mypos = base[e0] + __popcll(mm & below);
      base[e0] += __popcll(mm);
    }
    int sm_;
    if (mypos < CAPACITY) {
      eidx[e * CAPACITY + mypos] = f >> 1;
      sm_ = eb[e] + mypos;
    } else sm_ = -1;
    slotmap[f] = sm_;
  }
}

// ---------------- MoE GEMM1: 1D grid, expert = bid&7 (XCD pin), gl_lds staging ------
__global__ __launch_bounds__(256)
void moe_gemm1_kernel(const u16* __restrict__ hbf, const u16* __restrict__ w1T,
                      const float* __restrict__ b1, const int* __restrict__ eidx,
                      const int* __restrict__ counts, const int* __restrict__ ebase,
                      u16* __restrict__ h1)
{
  int bid = blockIdx.x;
  int e = bid & 7;
  int idx = bid >> 3;                 // m fastest within expert
  int m0 = (idx & 15) * 128;
  int n0 = (idx >> 4) * 128;
  int cnt = counts[e];
  if (m0 >= cnt) return;
  int base = ebase[e];
  __shared__ __align__(16) u16 As[128 * 64];
  __shared__ __align__(16) u16 Bs[128 * 64];
  __shared__ int rowtok[128];
  int tid = threadIdx.x;
  if (tid < 128) {
    int r = m0 + tid;
    rowtok[tid] = (r < cnt) ? eidx[e * CAPACITY + r] : 0;   // clamp: dead rows never stored
  }
  __syncthreads();
  const u16* BT = w1T + (size_t)e * IDIM * HDIM;
  f32x4 acc[4][4];
#pragma unroll
  for (int i = 0; i < 4; ++i)
#pragma unroll
    for (int j = 0; j < 4; ++j) acc[i][j] = (f32x4){0.f, 0.f, 0.f, 0.f};
  int w = tid >> 6, l = tid & 63;
  int lr = l & 15, lq = l >> 4;
  int wm = (w & 1) * 64, wn = (w >> 1) * 64;
  const u16* aptr[4]; const u16* bptr[4]; u16* adst[4]; u16* bdst[4];
#pragma unroll
  for (int p = 0; p < 4; ++p) {
    int flat = p * 256 + tid;
    int r = flat >> 3, c = flat & 7;
    int cs = (c ^ (r & 7)) * 8;
    aptr[p] = hbf + (size_t)rowtok[r] * HDIM + cs;
    bptr[p] = BT + (size_t)(n0 + r) * HDIM + cs;
    adst[p] = &As[(size_t)(p * 256 + w * 64) * 8];
    bdst[p] = &Bs[(size_t)(p * 256 + w * 64) * 8];
  }
  for (int k0 = 0; k0 < HDIM; k0 += 64) {
#pragma unroll
    for (int p = 0; p < 4; ++p) {
      gload_lds16(aptr[p] + k0, adst[p]);
      gload_lds16(bptr[p] + k0, bdst[p]);
    }
    __syncthreads();
#pragma unroll
    for (int s = 0; s < 2; ++s) {
      bf16x8 af[4], bfv[4];
#pragma unroll
      for (int i = 0; i < 4; ++i) {
        int mloc = wm + i * 16 + lr;
        af[i]  = *(const bf16x8*)&As[(mloc * 8 + ((s * 4 + lq) ^ (mloc & 7))) * 8];
        int n = wn + i * 16 + lr;
        bfv[i] = *(const bf16x8*)&Bs[(n * 8 + ((s * 4 + lq) ^ (n & 7))) * 8];
      }
#pragma unroll
      for (int i = 0; i < 4; ++i)
#pragma unroll
        for (int j = 0; j < 4; ++j)
          acc[i][j] = __builtin_amdgcn_mfma_f32_16x16x32_bf16(af[i], bfv[j], acc[i][j], 0, 0, 0);
    }
    __syncthreads();
  }
#pragma unroll
  for (int i = 0; i < 4; ++i)
#pragma unroll
    for (int j = 0; j < 4; ++j) {
      int col = n0 + wn + j * 16 + lr;
      float bb = b1[(size_t)e * IDIM + col];
#pragma unroll
      for (int r = 0; r < 4; ++r) {
        int rowl = m0 + wm + i * 16 + lq * 4 + r;
        if (rowl < cnt) {
          float y = acc[i][j][r] + bb;
          float g = 0.5f * y * (1.0f + erff(y * 0.70710678118654752f));
          h1[(size_t)(base + rowl) * IDIM + col] = f2bf(g);
        }
      }
    }
}

// ---------------- MoE GEMM2: 1D grid, expert = bid&7 (XCD pin), gl_lds staging ------
__global__ __launch_bounds__(256)
void moe_gemm2_kernel(const u16* __restrict__ h1, const u16* __restrict__ w2T,
                      const float* __restrict__ b2, const int* __restrict__ counts,
                      const int* __restrict__ ebase, u16* __restrict__ ybuf)
{
  int bid = blockIdx.x;
  int e = bid & 7;
  int idx = bid >> 3;                 // m fastest within expert
  int m0 = (idx & 15) * 128;
  int n0 = (idx >> 4) * 128;
  int cnt = counts[e];
  if (m0 >= cnt) return;
  int base = ebase[e];
  __shared__ __align__(16) u16 As[128 * 64];
  __shared__ __align__(16) u16 Bs[128 * 64];
  int tid = threadIdx.x;
  const u16* BT = w2T + (size_t)e * HDIM * IDIM;
  f32x4 acc[4][4];
#pragma unroll
  for (int i = 0; i < 4; ++i)
#pragma unroll
    for (int j = 0; j < 4; ++j) acc[i][j] = (f32x4){0.f, 0.f, 0.f, 0.f};
  int w = tid >> 6, l = tid & 63;
  int lr = l & 15, lq = l >> 4;
  int wm = (w & 1) * 64, wn = (w >> 1) * 64;
  const u16* aptr[4]; const u16* bptr[4]; u16* adst[4]; u16* bdst[4];
#pragma unroll
  for (int p = 0; p < 4; ++p) {
    int flat = p * 256 + tid;
    int r = flat >> 3, c = flat & 7;
    int cs = (c ^ (r & 7)) * 8;
    int rowg = m0 + r;
    if (rowg >= cnt) rowg = cnt - 1;  // clamp: dead rows never stored
    aptr[p] = h1 + (size_t)(base + rowg) * IDIM + cs;
    bptr[p] = BT + (size_t)(n0 + r) * IDIM + cs;
    adst[p] = &As[(size_t)(p * 256 + w * 64) * 8];
    bdst[p] = &Bs[(size_t)(p * 256 + w * 64) * 8];
  }
  for (int k0 = 0; k0 < IDIM; k0 += 64) {
#pragma unroll
    for (int p = 0; p < 4; ++p) {
      gload_lds16(aptr[p] + k0, adst[p]);
      gload_lds16(bptr[p] + k0, bdst[p]);
    }
    __syncthreads();
#pragma unroll
    for (int s = 0; s < 2; ++s) {
      bf16x8 af[4], bfv[4];
#pragma unroll
      for (int i = 0; i < 4; ++i) {
        int mloc = wm + i * 16 + lr;
        af[i]  = *(const bf16x8*)&As[(mloc * 8 + ((s * 4 + lq) ^ (mloc & 7))) * 8];
        int n = wn + i * 16 + lr;
        bfv[i] = *(const bf16x8*)&Bs[(n * 8 + ((s * 4 + lq) ^ (n & 7))) * 8];
      }
#pragma unroll
      for (int i = 0; i < 4; ++i)
#pragma unroll
        for (int j = 0; j < 4; ++j)
          acc[i][j] = __builtin_amdgcn_mfma_f32_16x16x32_bf16(af[i], bfv[j], acc[i][j], 0, 0, 0);
    }
    __syncthreads();
  }
#pragma unroll
  for (int i = 0; i < 4; ++i)
#pragma unroll
    for (int j = 0; j < 4; ++j) {
      int col = n0 + wn + j * 16 + lr;
      float bb = b2[(size_t)e * HDIM + col];
#pragma unroll
      for (int r = 0; r < 4; ++r) {
        int rowl = m0 + wm + i * 16 + lq * 4 + r;
        if (rowl < cnt)
          ybuf[(size_t)(base + rowl) * HDIM + col] = f2bf(acc[i][j][r] + bb);
      }
    }
}

// ---------------- final: h + sum_k tw_k * y[row_k] -> LayerNorm -> fp32 out ----------------
__global__ __launch_bounds__(256)
void final_kernel(const float* __restrict__ h, const u16* __restrict__ ybuf,
                  const int* __restrict__ slotmap, const float* __restrict__ tw,
                  const float* __restrict__ lnw, const float* __restrict__ lnb,
                  float* __restrict__ out)
{
  int t = blockIdx.x, tid = threadIdx.x;
  int s0 = slotmap[t * 2], s1 = slotmap[t * 2 + 1];
  float w0 = tw[t * 2], w1v = tw[t * 2 + 1];
  float4 hv = ((const float4*)(h + (size_t)t * HDIM))[tid];
  float vals[4] = {hv.x, hv.y, hv.z, hv.w};
  if (s0 >= 0) {
    const u16* yr = ybuf + (size_t)s0 * HDIM + tid * 4;
#pragma unroll
    for (int j = 0; j < 4; ++j) vals[j] += w0 * bf2f(yr[j]);
  }
  if (s1 >= 0) {
    const u16* yr = ybuf + (size_t)s1 * HDIM + tid * 4;
#pragma unroll
    for (int j = 0; j < 4; ++j) vals[j] += w1v * bf2f(yr[j]);
  }
  float s = vals[0] + vals[1] + vals[2] + vals[3];
  float q2 = vals[0] * vals[0] + vals[1] * vals[1] + vals[2] * vals[2] + vals[3] * vals[3];
  __shared__ float reds[4], redq[4];
  float wsv = wave_sum(s), wqv = wave_sum(q2);
  int wid = tid >> 6, l = tid & 63;
  if (l == 0) { reds[wid] = wsv; redq[wid] = wqv; }
  __syncthreads();
  float tot = reds[0] + reds[1] + reds[2] + reds[3];
  float totq = redq[0] + redq[1] + redq[2] + redq[3];
  float mu = tot / 1024.0f;
  float var = totq / 1024.0f - mu * mu;
  float inv = 1.0f / sqrtf(var + 1e-6f);
#pragma unroll
  for (int j = 0; j < 4; ++j) {
    int c = tid * 4 + j;
    out[(size_t)t * HDIM + c] = (vals[j] - mu) * inv * lnw[c] + lnb[c];
  }
}

extern "C" void kernel_launch(void* const* d_in, const int* in_sizes, int n_in,
                              void* d_out, int out_size, void* d_ws, size_t ws_size,
                              hipStream_t stream)
{
  const float* x      = (const float*)d_in[0];
  const float* qw     = (const float*)d_in[2];
  const float* qb     = (const float*)d_in[3];
  const float* kw     = (const float*)d_in[4];
  const float* kb     = (const float*)d_in[5];
  const float* vw     = (const float*)d_in[6];
  const float* vb     = (const float*)d_in[7];
  const float* ow     = (const float*)d_in[8];
  const float* ob     = (const float*)d_in[9];
  const float* rms_w  = (const float*)d_in[10];
  const float* gate_w = (const float*)d_in[11];
  const float* w1     = (const float*)d_in[12];
  const float* b1     = (const float*)d_in[13];
  const float* w2     = (const float*)d_in[14];
  const float* b2     = (const float*)d_in[15];
  const float* ln_w   = (const float*)d_in[16];
  const float* ln_b   = (const float*)d_in[17];

  char* ws = (char*)d_ws;
  const size_t MB = 1024ull * 1024ull;
  u16*   qbf    = (u16*)(ws + 0 * MB);     // 8MB bf16 q [bh][s][d]
  u16*   kbf    = (u16*)(ws + 8 * MB);     // 8MB
  u16*   vbf    = (u16*)(ws + 16 * MB);    // 8MB
  u16*   aobf   = (u16*)(ws + 24 * MB);    // 8MB bf16 attn-out [tok][H]
  u16*   xbf    = (u16*)(ws + 32 * MB);    // 8MB bf16 x
  u16*   wqT    = (u16*)(ws + 40 * MB);    // 2MB
  u16*   wkT    = (u16*)(ws + 42 * MB);    // 2MB
  u16*   wvT    = (u16*)(ws + 44 * MB);    // 2MB
  u16*   owT    = (u16*)(ws + 46 * MB);    // 2MB
  float* projbuf= (float*)(ws + 48 * MB);  // 16MB fp32 attn-proj out
  float* hbuf   = (float*)(ws + 64 * MB);  // 16MB fp32 h
  u16*   hbf    = (u16*)(ws + 80 * MB);    // 8MB bf16 h
  u16*   wT     = (u16*)(ws + 0 * MB);     // MoE weight^T staging, 32MB (q/k/v/ao dead)
  u16*   ybuf   = (u16*)(ws + 32 * MB);    // 16MB (xbf + w*T dead)
  u16*   h1buf  = (u16*)(ws + 88 * MB);    // 32MB
  char*  sm     = ws + 120 * MB;
  int*   ti      = (int*)(sm);
  float* tw      = (float*)(sm + 32 * 1024);
  int*   eidx    = (int*)(sm + 64 * 1024);
  int*   slotmap = (int*)(sm + 128 * 1024);
  int*   counts  = (int*)(sm + 160 * 1024);
  int*   ebase   = (int*)(sm + 164 * 1024);

  cvt_bf16_kernel<<<NTOK, 256, 0, stream>>>(x, xbf);
  transpose_cvt_kernel<<<dim3(32, 32, 1), 256, 0, stream>>>(qw, wqT, HDIM, HDIM);
  transpose_cvt_kernel<<<dim3(32, 32, 1), 256, 0, stream>>>(kw, wkT, HDIM, HDIM);
  transpose_cvt_kernel<<<dim3(32, 32, 1), 256, 0, stream>>>(vw, wvT, HDIM, HDIM);
  transpose_cvt_kernel<<<dim3(32, 32, 1), 256, 0, stream>>>(ow, owT, HDIM, HDIM);
  qkv_mfma_kernel<<<dim3(NTOK / 128, HDIM / 128, 3), 256, 0, stream>>>(
      xbf, wqT, wkT, wvT, qb, kb, vb, qbf, kbf, vbf);
  attn_mfma_kernel<<<NB * NHEAD * (SQL / 64), 256, 0, stream>>>(qbf, kbf, vbf, aobf);
  proj_mfma_kernel<<<dim3(NTOK / 128, HDIM / 128), 256, 0, stream>>>(
      aobf, owT, ob, projbuf);
  rmsnorm_kernel<<<NTOK, 256, 0, stream>>>(x, projbuf, rms_w, hbuf, hbf);
  transpose_cvt_kernel<<<dim3(IDIM / 32, HDIM / 32, NEXP), 256, 0, stream>>>(
      w1, wT, HDIM, IDIM);
  router_kernel<<<NTOK / 4, 256, 0, stream>>>(hbuf, gate_w, ti, tw);
  scan_kernel<<<1, 1024, 0, stream>>>(ti, eidx, counts, slotmap, ebase);
  moe_gemm1_kernel<<<dim3(NEXP * (CAPACITY / 128) * (IDIM / 128)), 256, 0, stream>>>(
      hbf, wT, b1, eidx, counts, ebase, h1buf);
  transpose_cvt_kernel<<<dim3(HDIM / 32, IDIM / 32, NEXP), 256, 0, stream>>>(
      w2, wT, IDIM, HDIM);
  moe_gemm2_kernel<<<dim3(NEXP * (CAPACITY / 128) * (HDIM / 128)), 256, 0, stream>>>(
      h1buf, wT, b2, counts, ebase, ybuf);
  final_kernel<<<NTOK, 256, 0, stream>>>(hbuf, ybuf, slotmap, tw, ln_w, ln_b,
                                         (float*)d_out);
}

// Round 6
// 526.681 us; speedup vs baseline: 2.6427x; 1.0140x over previous
//
#include <hip/hip_runtime.h>

#define NB 4
#define SQL 1024
#define HDIM 1024
#define NHEAD 16
#define HEADD 64
#define NEXP 8
#define IDIM 2048
#define NTOK (NB*SQL)
#define CAPACITY 2048
#define ATT_SCALE 0.125f

typedef unsigned short u16;
typedef __attribute__((ext_vector_type(8))) short bf16x8;
typedef __attribute__((ext_vector_type(8))) unsigned short u16x8;
typedef __attribute__((ext_vector_type(4))) float f32x4;

__device__ __forceinline__ u16 f2bf(float f) {
  union { float f; unsigned u; } x; x.f = f;
  unsigned r = (x.u + 0x7fffu + ((x.u >> 16) & 1u)) >> 16;
  return (u16)r;
}
__device__ __forceinline__ float bf2f(u16 b) {
  union { unsigned u; float f; } x; x.u = ((unsigned)b) << 16;
  return x.f;
}
__device__ __forceinline__ float wave_sum(float v) {
#pragma unroll
  for (int off = 32; off > 0; off >>= 1) v += __shfl_xor(v, off);
  return v;
}
// async global->LDS, 16B/lane; LDS dest must be wave-uniform base (+lane*16 implicit)
__device__ __forceinline__ void gload_lds16(const u16* g, u16* l) {
  __builtin_amdgcn_global_load_lds(
      (const __attribute__((address_space(1))) void*)g,
      (__attribute__((address_space(3))) void*)l, 16, 0, 0);
}

// ---------------- fp32 -> bf16 row convert (x) ----------------
__global__ __launch_bounds__(256)
void cvt_bf16_kernel(const float* __restrict__ in, u16* __restrict__ out)
{
  size_t i = (size_t)blockIdx.x * 1024 + threadIdx.x * 4;
  float4 v = *(const float4*)&in[i];
  ushort4 o = {f2bf(v.x), f2bf(v.y), f2bf(v.z), f2bf(v.w)};
  *(ushort4*)&out[i] = o;
}

// ---------------- transpose+convert: in fp32 [e][R][C] -> out bf16 [e][C][R] ----------------
__global__ __launch_bounds__(256)
void transpose_cvt_kernel(const float* __restrict__ in, u16* __restrict__ out,
                          int R, int C)
{
  int e = blockIdx.z;
  const float* ine = in + (size_t)e * R * C;
  u16* oute = out + (size_t)e * R * C;
  __shared__ u16 Ts[32 * 34];
  int tx = threadIdx.x & 31, ty = threadIdx.x >> 5;
  int r0 = blockIdx.y * 32, c0 = blockIdx.x * 32;
#pragma unroll
  for (int qq = 0; qq < 4; ++qq) {
    int rr = ty + qq * 8;
    Ts[tx * 34 + rr] = f2bf(ine[(size_t)(r0 + rr) * C + c0 + tx]);
  }
  __syncthreads();
#pragma unroll
  for (int qq = 0; qq < 4; ++qq) {
    int cc = ty + qq * 8;
    oute[(size_t)(c0 + cc) * R + r0 + tx] = Ts[cc * 34 + tx];
  }
}

// ===== MFMA GEMM cores: safe 2-phase double buffer =====
// stage(t+1) issued BEFORE compute(t); __syncthreads() at loop top drains.
// Full unroll -> cur is compile-time -> LDS halves disambiguated.

// ---------------- QKV projection: bf16 MFMA 128x128 tile, K=HDIM ----------------
__global__ __launch_bounds__(256)
void qkv_mfma_kernel(const u16* __restrict__ xbf,
                     const u16* __restrict__ wqT, const u16* __restrict__ wkT,
                     const u16* __restrict__ wvT,
                     const float* __restrict__ bq, const float* __restrict__ bk,
                     const float* __restrict__ bv,
                     u16* __restrict__ q, u16* __restrict__ k, u16* __restrict__ v)
{
  int mode = blockIdx.z;
  const u16* BT   = (mode == 0) ? wqT : (mode == 1) ? wkT : wvT;
  const float* bia = (mode == 0) ? bq : (mode == 1) ? bk : bv;
  u16* dst         = (mode == 0) ? q : (mode == 1) ? k : v;
  int m0 = blockIdx.x * 128, n0 = blockIdx.y * 128;
  __shared__ __align__(16) u16 As[2 * 128 * 64];
  __shared__ __align__(16) u16 Bs[2 * 128 * 64];
  int tid = threadIdx.x;
  f32x4 acc[4][4];
#pragma unroll
  for (int i = 0; i < 4; ++i)
#pragma unroll
    for (int j = 0; j < 4; ++j) acc[i][j] = (f32x4){0.f, 0.f, 0.f, 0.f};
  int w = tid >> 6, l = tid & 63;
  int lr = l & 15, lq = l >> 4;
  int wm = (w & 1) * 64, wn = (w >> 1) * 64;
  const u16* aptr[4]; const u16* bptr[4]; u16* adst[4]; u16* bdst[4];
#pragma unroll
  for (int p = 0; p < 4; ++p) {
    int flat = p * 256 + tid;
    int r = flat >> 3, c = flat & 7;
    int cs = (c ^ (r & 7)) * 8;
    aptr[p] = xbf + (size_t)(m0 + r) * HDIM + cs;
    bptr[p] = BT + (size_t)(n0 + r) * HDIM + cs;
    adst[p] = &As[(size_t)(p * 256 + w * 64) * 8];
    bdst[p] = &Bs[(size_t)(p * 256 + w * 64) * 8];
  }
  // prologue: stage tile 0 into buf 0
#pragma unroll
  for (int p = 0; p < 4; ++p) { gload_lds16(aptr[p], adst[p]); gload_lds16(bptr[p], bdst[p]); }
  const int NT = HDIM / 64;
#pragma unroll
  for (int t = 0; t < NT; ++t) {
    const int cur = t & 1;
    __syncthreads();                       // tile-t loads landed; prev-tile reads done
    if (t + 1 < NT) {                      // issue next tile: in flight across compute
      int k0 = (t + 1) * 64;
      int off = (cur ^ 1) * (128 * 64);
#pragma unroll
      for (int p = 0; p < 4; ++p) {
        gload_lds16(aptr[p] + k0, adst[p] + off);
        gload_lds16(bptr[p] + k0, bdst[p] + off);
      }
    }
    const u16* Ab = As + cur * (128 * 64);
    const u16* Bb = Bs + cur * (128 * 64);
#pragma unroll
    for (int s = 0; s < 2; ++s) {
      bf16x8 af[4], bfv[4];
#pragma unroll
      for (int i = 0; i < 4; ++i) {
        int mloc = wm + i * 16 + lr;
        af[i]  = *(const bf16x8*)&Ab[(mloc * 8 + ((s * 4 + lq) ^ (mloc & 7))) * 8];
        int n = wn + i * 16 + lr;
        bfv[i] = *(const bf16x8*)&Bb[(n * 8 + ((s * 4 + lq) ^ (n & 7))) * 8];
      }
#pragma unroll
      for (int i = 0; i < 4; ++i)
#pragma unroll
        for (int j = 0; j < 4; ++j)
          acc[i][j] = __builtin_amdgcn_mfma_f32_16x16x32_bf16(af[i], bfv[j], acc[i][j], 0, 0, 0);
    }
  }
#pragma unroll
  for (int i = 0; i < 4; ++i)
#pragma unroll
    for (int j = 0; j < 4; ++j) {
      int col = n0 + wn + j * 16 + lr;
      float bb = bia[col];
      int hh = col >> 6, d = col & 63;
#pragma unroll
      for (int r = 0; r < 4; ++r) {
        int tg = m0 + wm + i * 16 + lq * 4 + r;
        int bi = tg >> 10, s = tg & 1023;
        dst[((size_t)(bi * NHEAD + hh) * SQL + s) * HEADD + d] = f2bf(acc[i][j][r] + bb);
      }
    }
}

// ---------------- O-projection: bf16 MFMA, out fp32 [NTOK][HDIM] + bias ----------------
__global__ __launch_bounds__(256)
void proj_mfma_kernel(const u16* __restrict__ aobf, const u16* __restrict__ owT,
                      const float* __restrict__ ob, float* __restrict__ out)
{
  int m0 = blockIdx.x * 128, n0 = blockIdx.y * 128;
  __shared__ __align__(16) u16 As[2 * 128 * 64];
  __shared__ __align__(16) u16 Bs[2 * 128 * 64];
  int tid = threadIdx.x;
  f32x4 acc[4][4];
#pragma unroll
  for (int i = 0; i < 4; ++i)
#pragma unroll
    for (int j = 0; j < 4; ++j) acc[i][j] = (f32x4){0.f, 0.f, 0.f, 0.f};
  int w = tid >> 6, l = tid & 63;
  int lr = l & 15, lq = l >> 4;
  int wm = (w & 1) * 64, wn = (w >> 1) * 64;
  const u16* aptr[4]; const u16* bptr[4]; u16* adst[4]; u16* bdst[4];
#pragma unroll
  for (int p = 0; p < 4; ++p) {
    int flat = p * 256 + tid;
    int r = flat >> 3, c = flat & 7;
    int cs = (c ^ (r & 7)) * 8;
    aptr[p] = aobf + (size_t)(m0 + r) * HDIM + cs;
    bptr[p] = owT + (size_t)(n0 + r) * HDIM + cs;
    adst[p] = &As[(size_t)(p * 256 + w * 64) * 8];
    bdst[p] = &Bs[(size_t)(p * 256 + w * 64) * 8];
  }
#pragma unroll
  for (int p = 0; p < 4; ++p) { gload_lds16(aptr[p], adst[p]); gload_lds16(bptr[p], bdst[p]); }
  const int NT = HDIM / 64;
#pragma unroll
  for (int t = 0; t < NT; ++t) {
    const int cur = t & 1;
    __syncthreads();
    if (t + 1 < NT) {
      int k0 = (t + 1) * 64;
      int off = (cur ^ 1) * (128 * 64);
#pragma unroll
      for (int p = 0; p < 4; ++p) {
        gload_lds16(aptr[p] + k0, adst[p] + off);
        gload_lds16(bptr[p] + k0, bdst[p] + off);
      }
    }
    const u16* Ab = As + cur * (128 * 64);
    const u16* Bb = Bs + cur * (128 * 64);
#pragma unroll
    for (int s = 0; s < 2; ++s) {
      bf16x8 af[4], bfv[4];
#pragma unroll
      for (int i = 0; i < 4; ++i) {
        int mloc = wm + i * 16 + lr;
        af[i]  = *(const bf16x8*)&Ab[(mloc * 8 + ((s * 4 + lq) ^ (mloc & 7))) * 8];
        int n = wn + i * 16 + lr;
        bfv[i] = *(const bf16x8*)&Bb[(n * 8 + ((s * 4 + lq) ^ (n & 7))) * 8];
      }
#pragma unroll
      for (int i = 0; i < 4; ++i)
#pragma unroll
        for (int j = 0; j < 4; ++j)
          acc[i][j] = __builtin_amdgcn_mfma_f32_16x16x32_bf16(af[i], bfv[j], acc[i][j], 0, 0, 0);
    }
  }
#pragma unroll
  for (int i = 0; i < 4; ++i)
#pragma unroll
    for (int j = 0; j < 4; ++j) {
      int col = n0 + wn + j * 16 + lr;
      float bb = ob[col];
#pragma unroll
      for (int r = 0; r < 4; ++r) {
        int tg = m0 + wm + i * 16 + lq * 4 + r;
        out[(size_t)tg * HDIM + col] = acc[i][j][r] + bb;
      }
    }
}

// ---------------- flash attention, bf16 MFMA (round-4 verified version) ----------------
__global__ __launch_bounds__(256)
void attn_mfma_kernel(const u16* __restrict__ q, const u16* __restrict__ k,
                      const u16* __restrict__ v, u16* __restrict__ ao)
{
  __shared__ __align__(16) u16 VT[64 * 72];       // V^T [d][key], stride 72
  __shared__ __align__(16) u16 Pl[4][16 * 72];    // per-wave P [q][key]
  int bid = blockIdx.x;
  int bh = bid & 63;
  int qt = 15 - (bid >> 6);
  int q0 = qt * 64;
  int tid = threadIdx.x;
  int w = tid >> 6, l = tid & 63;
  int lr = l & 15, lq = l >> 4;

  const u16* qp = q + ((size_t)bh * SQL + q0 + w * 16 + lr) * HEADD + lq * 8;
  bf16x8 qf0 = *(const bf16x8*)qp;
  bf16x8 qf1 = *(const bf16x8*)(qp + 32);

  float mrow[4], lrow[4];
  f32x4 Ot[4];
#pragma unroll
  for (int r = 0; r < 4; ++r) { mrow[r] = -1e30f; lrow[r] = 0.f; }
#pragma unroll
  for (int j = 0; j < 4; ++j) Ot[j] = (f32x4){0.f, 0.f, 0.f, 0.f};

  int vkey = 2 * (l & 31);
  int vd0 = w * 16 + (l >> 5) * 8;

  for (int kb = 0; kb <= q0; kb += 64) {
    __syncthreads();
    {
      const u16* vp = v + ((size_t)bh * SQL + kb + vkey) * HEADD + vd0;
      u16x8 a = *(const u16x8*)vp;
      u16x8 b = *(const u16x8*)(vp + HEADD);
#pragma unroll
      for (int e = 0; e < 8; ++e) {
        ushort2 pr = {a[e], b[e]};
        *(ushort2*)&VT[(vd0 + e) * 72 + vkey] = pr;
      }
    }
    f32x4 sacc[4];
#pragma unroll
    for (int j = 0; j < 4; ++j) sacc[j] = (f32x4){0.f, 0.f, 0.f, 0.f};
    const u16* kp = k + ((size_t)bh * SQL + kb + lr) * HEADD + lq * 8;
#pragma unroll
    for (int j = 0; j < 4; ++j) {
      bf16x8 kf0 = *(const bf16x8*)(kp + (size_t)j * 16 * HEADD);
      bf16x8 kf1 = *(const bf16x8*)(kp + (size_t)j * 16 * HEADD + 32);
      sacc[j] = __builtin_amdgcn_mfma_f32_16x16x32_bf16(qf0, kf0, sacc[j], 0, 0, 0);
      sacc[j] = __builtin_amdgcn_mfma_f32_16x16x32_bf16(qf1, kf1, sacc[j], 0, 0, 0);
    }
    bool diag = (kb == q0);
    float pv[4][4];
#pragma unroll
    for (int r = 0; r < 4; ++r) {
      float sv[4];
      float rm = -1e30f;
#pragma unroll
      for (int j = 0; j < 4; ++j) {
        float s0 = sacc[j][r] * ATT_SCALE;
        if (diag && (j * 16 + lr) > (w * 16 + lq * 4 + r)) s0 = -1e30f;
        sv[j] = s0;
        rm = fmaxf(rm, s0);
      }
      rm = fmaxf(rm, __shfl_xor(rm, 1));
      rm = fmaxf(rm, __shfl_xor(rm, 2));
      rm = fmaxf(rm, __shfl_xor(rm, 4));
      rm = fmaxf(rm, __shfl_xor(rm, 8));
      float mnew = fmaxf(mrow[r], rm);
      float alpha = __expf(mrow[r] - mnew);
      mrow[r] = mnew;
      float rl = 0.f;
#pragma unroll
      for (int j = 0; j < 4; ++j) {
        float p = __expf(sv[j] - mnew);
        pv[j][r] = p;
        rl += p;
      }
      rl += __shfl_xor(rl, 1);
      rl += __shfl_xor(rl, 2);
      rl += __shfl_xor(rl, 4);
      rl += __shfl_xor(rl, 8);
      lrow[r] = lrow[r] * alpha + rl;
#pragma unroll
      for (int j2 = 0; j2 < 4; ++j2) Ot[j2][r] *= alpha;
    }
#pragma unroll
    for (int j = 0; j < 4; ++j)
#pragma unroll
      for (int r = 0; r < 4; ++r)
        Pl[w][(lq * 4 + r) * 72 + j * 16 + lr] = f2bf(pv[j][r]);
    __syncthreads();
    const u16* pbase = &Pl[w][lr * 72];
#pragma unroll
    for (int s = 0; s < 2; ++s) {
      bf16x8 pa = *(const bf16x8*)(pbase + s * 32 + lq * 8);
#pragma unroll
      for (int j2 = 0; j2 < 4; ++j2) {
        bf16x8 vb = *(const bf16x8*)&VT[(j2 * 16 + lr) * 72 + s * 32 + lq * 8];
        Ot[j2] = __builtin_amdgcn_mfma_f32_16x16x32_bf16(pa, vb, Ot[j2], 0, 0, 0);
      }
    }
  }
  int b = bh >> 4, hh = bh & 15;
#pragma unroll
  for (int r = 0; r < 4; ++r) {
    float invl = 1.0f / lrow[r];
    int row = q0 + w * 16 + lq * 4 + r;
#pragma unroll
    for (int j2 = 0; j2 < 4; ++j2)
      ao[((size_t)(b * SQL + row)) * HDIM + hh * HEADD + j2 * 16 + lr] =
          f2bf(Ot[j2][r] * invl);
  }
}

// ---------------- residual + RMSNorm (fp32 h out + bf16 copy) ----------------
__global__ __launch_bounds__(256)
void rmsnorm_kernel(const float* __restrict__ x, const float* __restrict__ p,
                    const float* __restrict__ w, float* __restrict__ out,
                    u16* __restrict__ outbf)
{
  int t = blockIdx.x, tid = threadIdx.x;
  float4 xv = ((const float4*)(x + (size_t)t * HDIM))[tid];
  float4 pv = ((const float4*)(p + (size_t)t * HDIM))[tid];
  float4 s = {xv.x + pv.x, xv.y + pv.y, xv.z + pv.z, xv.w + pv.w};
  float ss = s.x * s.x + s.y * s.y + s.z * s.z + s.w * s.w;
  __shared__ float red[4];
  float wsv = wave_sum(ss);
  int wid = tid >> 6, l = tid & 63;
  if (l == 0) red[wid] = wsv;
  __syncthreads();
  float tot = red[0] + red[1] + red[2] + red[3];
  float inv = 1.0f / sqrtf(tot / (float)HDIM + 1e-6f);
  float4 wv = ((const float4*)w)[tid];
  float4 o = {s.x * inv * wv.x, s.y * inv * wv.y, s.z * inv * wv.z, s.w * inv * wv.w};
  ((float4*)(out + (size_t)t * HDIM))[tid] = o;
  ushort4 ob = {f2bf(o.x), f2bf(o.y), f2bf(o.z), f2bf(o.w)};
  ((ushort4*)(outbf + (size_t)t * HDIM))[tid] = ob;
}

// ---------------- router: logits, softmax, top-2, weight norm ----------------
__global__ __launch_bounds__(256)
void router_kernel(const float* __restrict__ h, const float* __restrict__ gw,
                   int* __restrict__ ti, float* __restrict__ tw)
{
  int wid = threadIdx.x >> 6, l = threadIdx.x & 63;
  int t = blockIdx.x * 4 + wid;
  const float* hr = h + (size_t)t * HDIM;
  float hv[16];
#pragma unroll
  for (int j = 0; j < 16; ++j) hv[j] = hr[l + 64 * j];
  float lg[NEXP];
#pragma unroll
  for (int e = 0; e < NEXP; ++e) {
    const float* g = gw + (size_t)e * HDIM;
    float p = 0.f;
#pragma unroll
    for (int j = 0; j < 16; ++j) p += hv[j] * g[l + 64 * j];
    lg[e] = wave_sum(p);
  }
  if (l == 0) {
    int i1 = 0; float m1 = lg[0];
#pragma unroll
    for (int e = 1; e < NEXP; ++e) if (lg[e] > m1) { m1 = lg[e]; i1 = e; }
    int i2 = 0; float m2 = -1e30f;
#pragma unroll
    for (int e = 0; e < NEXP; ++e) if (e != i1 && lg[e] > m2) { m2 = lg[e]; i2 = e; }
    float se = 0.f;
#pragma unroll
    for (int e = 0; e < NEXP; ++e) se += expf(lg[e] - m1);
    float p1 = 1.0f / se;
    float p2 = expf(m2 - m1) / se;
    float denom = p1 + p2 + 1e-20f;
    tw[t * 2]     = p1 / denom * 0.5f;
    tw[t * 2 + 1] = p2 / denom * 0.5f;
    ti[t * 2]     = i1;
    ti[t * 2 + 1] = i2;
  }
}

// ---------------- parallel deterministic capacity scan (16 waves, 3 phases) ----------------
__global__ __launch_bounds__(1024)
void scan_kernel(const int* __restrict__ ti, int* __restrict__ eidx,
                 int* __restrict__ counts, int* __restrict__ slotmap,
                 int* __restrict__ ebase)
{
  __shared__ int wc[16][NEXP];
  __shared__ int wbase[16][NEXP];
  __shared__ int tot[NEXP];
  __shared__ int eb[NEXP];
  int tid = threadIdx.x;
  int w = tid >> 6, l = tid & 63;
  unsigned long long below = (l == 0) ? 0ull : ((~0ull) >> (64 - l));
  const int CH = (NTOK * 2) / 16;
  const int RND = CH / 64;
  int ev[RND];
  int myc[NEXP];
#pragma unroll
  for (int e = 0; e < NEXP; ++e) myc[e] = 0;
#pragma unroll
  for (int c2 = 0; c2 < RND; ++c2) {
    int f = w * CH + c2 * 64 + l;
    int e = ti[f];
    ev[c2] = e;
#pragma unroll
    for (int e0 = 0; e0 < NEXP; ++e0)
      myc[e0] += __popcll(__ballot(e == e0));
  }
  if (l == 0) {
#pragma unroll
    for (int e = 0; e < NEXP; ++e) wc[w][e] = myc[e];
  }
  __syncthreads();
  if (tid < NEXP) {
    int run = 0;
#pragma unroll
    for (int ww = 0; ww < 16; ++ww) { wbase[ww][tid] = run; run += wc[ww][tid]; }
    tot[tid] = run;
    counts[tid] = (run < CAPACITY) ? run : CAPACITY;
  }
  __syncthreads();
  if (tid == 0) {
    int run = 0;
#pragma unroll
    for (int e = 0; e < NEXP; ++e) {
      eb[e] = run;
      ebase[e] = run;
      int c = tot[e];
      run += (c < CAPACITY) ? c : CAPACITY;
    }
  }
  __syncthreads();
  int base[NEXP];
#pragma unroll
  for (int e = 0; e < NEXP; ++e) base[e] = wbase[w][e];
#pragma unroll
  for (int c2 = 0; c2 < RND; ++c2) {
    int f = w * CH + c2 * 64 + l;
    int e = ev[c2];
    int mypos = 0;
#pragma unroll
    for (int e0 = 0; e0 < NEXP; ++e0) {
      unsigned long long mm = __ballot(e == e0);
      if (e == e0) mypos = base[e0] + __popcll(mm & below);
      base[e0] += __popcll(mm);
    }
    int sm_;
    if (mypos < CAPACITY) {
      eidx[e * CAPACITY + mypos] = f >> 1;
      sm_ = eb[e] + mypos;
    } else sm_ = -1;
    slotmap[f] = sm_;
  }
}

// ---------------- MoE GEMM1: 1D grid, expert = bid&7 (XCD pin), 2-phase dbuf ------
__global__ __launch_bounds__(256)
void moe_gemm1_kernel(const u16* __restrict__ hbf, const u16* __restrict__ w1T,
                      const float* __restrict__ b1, const int* __restrict__ eidx,
                      const int* __restrict__ counts, const int* __restrict__ ebase,
                      u16* __restrict__ h1)
{
  int bid = blockIdx.x;
  int e = bid & 7;
  int idx = bid >> 3;
  int m0 = (idx & 15) * 128;
  int n0 = (idx >> 4) * 128;
  int cnt = counts[e];
  if (m0 >= cnt) return;
  int base = ebase[e];
  __shared__ __align__(16) u16 As[2 * 128 * 64];
  __shared__ __align__(16) u16 Bs[2 * 128 * 64];
  __shared__ int rowtok[128];
  int tid = threadIdx.x;
  if (tid < 128) {
    int r = m0 + tid;
    rowtok[tid] = (r < cnt) ? eidx[e * CAPACITY + r] : 0;
  }
  __syncthreads();
  const u16* BT = w1T + (size_t)e * IDIM * HDIM;
  f32x4 acc[4][4];
#pragma unroll
  for (int i = 0; i < 4; ++i)
#pragma unroll
    for (int j = 0; j < 4; ++j) acc[i][j] = (f32x4){0.f, 0.f, 0.f, 0.f};
  int w = tid >> 6, l = tid & 63;
  int lr = l & 15, lq = l >> 4;
  int wm = (w & 1) * 64, wn = (w >> 1) * 64;
  const u16* aptr[4]; const u16* bptr[4]; u16* adst[4]; u16* bdst[4];
#pragma unroll
  for (int p = 0; p < 4; ++p) {
    int flat = p * 256 + tid;
    int r = flat >> 3, c = flat & 7;
    int cs = (c ^ (r & 7)) * 8;
    aptr[p] = hbf + (size_t)rowtok[r] * HDIM + cs;
    bptr[p] = BT + (size_t)(n0 + r) * HDIM + cs;
    adst[p] = &As[(size_t)(p * 256 + w * 64) * 8];
    bdst[p] = &Bs[(size_t)(p * 256 + w * 64) * 8];
  }
#pragma unroll
  for (int p = 0; p < 4; ++p) { gload_lds16(aptr[p], adst[p]); gload_lds16(bptr[p], bdst[p]); }
  const int NT = HDIM / 64;
#pragma unroll
  for (int t = 0; t < NT; ++t) {
    const int cur = t & 1;
    __syncthreads();
    if (t + 1 < NT) {
      int k0 = (t + 1) * 64;
      int off = (cur ^ 1) * (128 * 64);
#pragma unroll
      for (int p = 0; p < 4; ++p) {
        gload_lds16(aptr[p] + k0, adst[p] + off);
        gload_lds16(bptr[p] + k0, bdst[p] + off);
      }
    }
    const u16* Ab = As + cur * (128 * 64);
    const u16* Bb = Bs + cur * (128 * 64);
#pragma unroll
    for (int s = 0; s < 2; ++s) {
      bf16x8 af[4], bfv[4];
#pragma unroll
      for (int i = 0; i < 4; ++i) {
        int mloc = wm + i * 16 + lr;
        af[i]  = *(const bf16x8*)&Ab[(mloc * 8 + ((s * 4 + lq) ^ (mloc & 7))) * 8];
        int n = wn + i * 16 + lr;
        bfv[i] = *(const bf16x8*)&Bb[(n * 8 + ((s * 4 + lq) ^ (n & 7))) * 8];
      }
#pragma unroll
      for (int i = 0; i < 4; ++i)
#pragma unroll
        for (int j = 0; j < 4; ++j)
          acc[i][j] = __builtin_amdgcn_mfma_f32_16x16x32_bf16(af[i], bfv[j], acc[i][j], 0, 0, 0);
    }
  }
#pragma unroll
  for (int i = 0; i < 4; ++i)
#pragma unroll
    for (int j = 0; j < 4; ++j) {
      int col = n0 + wn + j * 16 + lr;
      float bb = b1[(size_t)e * IDIM + col];
#pragma unroll
      for (int r = 0; r < 4; ++r) {
        int rowl = m0 + wm + i * 16 + lq * 4 + r;
        if (rowl < cnt) {
          float y = acc[i][j][r] + bb;
          float g = 0.5f * y * (1.0f + erff(y * 0.70710678118654752f));
          h1[(size_t)(base + rowl) * IDIM + col] = f2bf(g);
        }
      }
    }
}

// ---------------- MoE GEMM2: 1D grid, expert = bid&7 (XCD pin), 2-phase dbuf ------
__global__ __launch_bounds__(256)
void moe_gemm2_kernel(const u16* __restrict__ h1, const u16* __restrict__ w2T,
                      const float* __restrict__ b2, const int* __restrict__ counts,
                      const int* __restrict__ ebase, u16* __restrict__ ybuf)
{
  int bid = blockIdx.x;
  int e = bid & 7;
  int idx = bid >> 3;
  int m0 = (idx & 15) * 128;
  int n0 = (idx >> 4) * 128;
  int cnt = counts[e];
  if (m0 >= cnt) return;
  int base = ebase[e];
  __shared__ __align__(16) u16 As[2 * 128 * 64];
  __shared__ __align__(16) u16 Bs[2 * 128 * 64];
  int tid = threadIdx.x;
  const u16* BT = w2T + (size_t)e * HDIM * IDIM;
  f32x4 acc[4][4];
#pragma unroll
  for (int i = 0; i < 4; ++i)
#pragma unroll
    for (int j = 0; j < 4; ++j) acc[i][j] = (f32x4){0.f, 0.f, 0.f, 0.f};
  int w = tid >> 6, l = tid & 63;
  int lr = l & 15, lq = l >> 4;
  int wm = (w & 1) * 64, wn = (w >> 1) * 64;
  const u16* aptr[4]; const u16* bptr[4]; u16* adst[4]; u16* bdst[4];
#pragma unroll
  for (int p = 0; p < 4; ++p) {
    int flat = p * 256 + tid;
    int r = flat >> 3, c = flat & 7;
    int cs = (c ^ (r & 7)) * 8;
    int rowg = m0 + r;
    if (rowg >= cnt) rowg = cnt - 1;
    aptr[p] = h1 + (size_t)(base + rowg) * IDIM + cs;
    bptr[p] = BT + (size_t)(n0 + r) * IDIM + cs;
    adst[p] = &As[(size_t)(p * 256 + w * 64) * 8];
    bdst[p] = &Bs[(size_t)(p * 256 + w * 64) * 8];
  }
#pragma unroll
  for (int p = 0; p < 4; ++p) { gload_lds16(aptr[p], adst[p]); gload_lds16(bptr[p], bdst[p]); }
  const int NT = IDIM / 64;
#pragma unroll
  for (int t = 0; t < NT; ++t) {
    const int cur = t & 1;
    __syncthreads();
    if (t + 1 < NT) {
      int k0 = (t + 1) * 64;
      int off = (cur ^ 1) * (128 * 64);
#pragma unroll
      for (int p = 0; p < 4; ++p) {
        gload_lds16(aptr[p] + k0, adst[p] + off);
        gload_lds16(bptr[p] + k0, bdst[p] + off);
      }
    }
    const u16* Ab = As + cur * (128 * 64);
    const u16* Bb = Bs + cur * (128 * 64);
#pragma unroll
    for (int s = 0; s < 2; ++s) {
      bf16x8 af[4], bfv[4];
#pragma unroll
      for (int i = 0; i < 4; ++i) {
        int mloc = wm + i * 16 + lr;
        af[i]  = *(const bf16x8*)&Ab[(mloc * 8 + ((s * 4 + lq) ^ (mloc & 7))) * 8];
        int n = wn + i * 16 + lr;
        bfv[i] = *(const bf16x8*)&Bb[(n * 8 + ((s * 4 + lq) ^ (n & 7))) * 8];
      }
#pragma unroll
      for (int i = 0; i < 4; ++i)
#pragma unroll
        for (int j = 0; j < 4; ++j)
          acc[i][j] = __builtin_amdgcn_mfma_f32_16x16x32_bf16(af[i], bfv[j], acc[i][j], 0, 0, 0);
    }
  }
#pragma unroll
  for (int i = 0; i < 4; ++i)
#pragma unroll
    for (int j = 0; j < 4; ++j) {
      int col = n0 + wn + j * 16 + lr;
      float bb = b2[(size_t)e * HDIM + col];
#pragma unroll
      for (int r = 0; r < 4; ++r) {
        int rowl = m0 + wm + i * 16 + lq * 4 + r;
        if (rowl < cnt)
          ybuf[(size_t)(base + rowl) * HDIM + col] = f2bf(acc[i][j][r] + bb);
      }
    }
}

// ---------------- final: h + sum_k tw_k * y[row_k] -> LayerNorm -> fp32 out ----------------
__global__ __launch_bounds__(256)
void final_kernel(const float* __restrict__ h, const u16* __restrict__ ybuf,
                  const int* __restrict__ slotmap, const float* __restrict__ tw,
                  const float* __restrict__ lnw, const float* __restrict__ lnb,
                  float* __restrict__ out)
{
  int t = blockIdx.x, tid = threadIdx.x;
  int s0 = slotmap[t * 2], s1 = slotmap[t * 2 + 1];
  float w0 = tw[t * 2], w1v = tw[t * 2 + 1];
  float4 hv = ((const float4*)(h + (size_t)t * HDIM))[tid];
  float vals[4] = {hv.x, hv.y, hv.z, hv.w};
  if (s0 >= 0) {
    const u16* yr = ybuf + (size_t)s0 * HDIM + tid * 4;
#pragma unroll
    for (int j = 0; j < 4; ++j) vals[j] += w0 * bf2f(yr[j]);
  }
  if (s1 >= 0) {
    const u16* yr = ybuf + (size_t)s1 * HDIM + tid * 4;
#pragma unroll
    for (int j = 0; j < 4; ++j) vals[j] += w1v * bf2f(yr[j]);
  }
  float s = vals[0] + vals[1] + vals[2] + vals[3];
  float q2 = vals[0] * vals[0] + vals[1] * vals[1] + vals[2] * vals[2] + vals[3] * vals[3];
  __shared__ float reds[4], redq[4];
  float wsv = wave_sum(s), wqv = wave_sum(q2);
  int wid = tid >> 6, l = tid & 63;
  if (l == 0) { reds[wid] = wsv; redq[wid] = wqv; }
  __syncthreads();
  float tot = reds[0] + reds[1] + reds[2] + reds[3];
  float totq = redq[0] + redq[1] + redq[2] + redq[3];
  float mu = tot / 1024.0f;
  float var = totq / 1024.0f - mu * mu;
  float inv = 1.0f / sqrtf(var + 1e-6f);
#pragma unroll
  for (int j = 0; j < 4; ++j) {
    int c = tid * 4 + j;
    out[(size_t)t * HDIM + c] = (vals[j] - mu) * inv * lnw[c] + lnb[c];
  }
}

extern "C" void kernel_launch(void* const* d_in, const int* in_sizes, int n_in,
                              void* d_out, int out_size, void* d_ws, size_t ws_size,
                              hipStream_t stream)
{
  const float* x      = (const float*)d_in[0];
  const float* qw     = (const float*)d_in[2];
  const float* qb     = (const float*)d_in[3];
  const float* kw     = (const float*)d_in[4];
  const float* kb     = (const float*)d_in[5];
  const float* vw     = (const float*)d_in[6];
  const float* vb     = (const float*)d_in[7];
  const float* ow     = (const float*)d_in[8];
  const float* ob     = (const float*)d_in[9];
  const float* rms_w  = (const float*)d_in[10];
  const float* gate_w = (const float*)d_in[11];
  const float* w1     = (const float*)d_in[12];
  const float* b1     = (const float*)d_in[13];
  const float* w2     = (const float*)d_in[14];
  const float* b2     = (const float*)d_in[15];
  const float* ln_w   = (const float*)d_in[16];
  const float* ln_b   = (const float*)d_in[17];

  char* ws = (char*)d_ws;
  const size_t MB = 1024ull * 1024ull;
  u16*   qbf    = (u16*)(ws + 0 * MB);     // 8MB bf16 q [bh][s][d]
  u16*   kbf    = (u16*)(ws + 8 * MB);     // 8MB
  u16*   vbf    = (u16*)(ws + 16 * MB);    // 8MB
  u16*   aobf   = (u16*)(ws + 24 * MB);    // 8MB bf16 attn-out [tok][H]
  u16*   xbf    = (u16*)(ws + 32 * MB);    // 8MB bf16 x
  u16*   wqT    = (u16*)(ws + 40 * MB);    // 2MB
  u16*   wkT    = (u16*)(ws + 42 * MB);    // 2MB
  u16*   wvT    = (u16*)(ws + 44 * MB);    // 2MB
  u16*   owT    = (u16*)(ws + 46 * MB);    // 2MB
  float* projbuf= (float*)(ws + 48 * MB);  // 16MB fp32 attn-proj out
  float* hbuf   = (float*)(ws + 64 * MB);  // 16MB fp32 h
  u16*   hbf    = (u16*)(ws + 80 * MB);    // 8MB bf16 h
  u16*   wT     = (u16*)(ws + 0 * MB);     // MoE weight^T staging, 32MB (q/k/v/ao dead)
  u16*   ybuf   = (u16*)(ws + 32 * MB);    // 16MB (xbf + w*T dead)
  u16*   h1buf  = (u16*)(ws + 88 * MB);    // 32MB
  char*  sm     = ws + 120 * MB;
  int*   ti      = (int*)(sm);
  float* tw      = (float*)(sm + 32 * 1024);
  int*   eidx    = (int*)(sm + 64 * 1024);
  int*   slotmap = (int*)(sm + 128 * 1024);
  int*   counts  = (int*)(sm + 160 * 1024);
  int*   ebase   = (int*)(sm + 164 * 1024);

  cvt_bf16_kernel<<<NTOK, 256, 0, stream>>>(x, xbf);
  transpose_cvt_kernel<<<dim3(32, 32, 1), 256, 0, stream>>>(qw, wqT, HDIM, HDIM);
  transpose_cvt_kernel<<<dim3(32, 32, 1), 256, 0, stream>>>(kw, wkT, HDIM, HDIM);
  transpose_cvt_kernel<<<dim3(32, 32, 1), 256, 0, stream>>>(vw, wvT, HDIM, HDIM);
  transpose_cvt_kernel<<<dim3(32, 32, 1), 256, 0, stream>>>(ow, owT, HDIM, HDIM);
  qkv_mfma_kernel<<<dim3(NTOK / 128, HDIM / 128, 3), 256, 0, stream>>>(
      xbf, wqT, wkT, wvT, qb, kb, vb, qbf, kbf, vbf);
  attn_mfma_kernel<<<NB * NHEAD * (SQL / 64), 256, 0, stream>>>(qbf, kbf, vbf, aobf);
  proj_mfma_kernel<<<dim3(NTOK / 128, HDIM / 128), 256, 0, stream>>>(
      aobf, owT, ob, projbuf);
  rmsnorm_kernel<<<NTOK, 256, 0, stream>>>(x, projbuf, rms_w, hbuf, hbf);
  transpose_cvt_kernel<<<dim3(IDIM / 32, HDIM / 32, NEXP), 256, 0, stream>>>(
      w1, wT, HDIM, IDIM);
  router_kernel<<<NTOK / 4, 256, 0, stream>>>(hbuf, gate_w, ti, tw);
  scan_kernel<<<1, 1024, 0, stream>>>(ti, eidx, counts, slotmap, ebase);
  moe_gemm1_kernel<<<dim3(NEXP * (CAPACITY / 128) * (IDIM / 128)), 256, 0, stream>>>(
      hbf, wT, b1, eidx, counts, ebase, h1buf);
  transpose_cvt_kernel<<<dim3(HDIM / 32, IDIM / 32, NEXP), 256, 0, stream>>>(
      w2, wT, IDIM, HDIM);
  moe_gemm2_kernel<<<dim3(NEXP * (CAPACITY / 128) * (HDIM / 128)), 256, 0, stream>>>(
      h1buf, wT, b2, counts, ebase, ybuf);
  final_kernel<<<NTOK, 256, 0, stream>>>(hbuf, ybuf, slotmap, tw, ln_w, ln_b,
                                         (float*)d_out);
}